// Round 3
// baseline (27466.162 us; speedup 1.0000x reference)
//
#include <hip/hip_runtime.h>
#include <math.h>

#define THREADS 256

static inline int ceil_div(int a, int b) { return (a + b - 1) / b; }

__device__ __forceinline__ float wave_sum_all(float v) {
#pragma unroll
  for (int m = 1; m < 64; m <<= 1) v += __shfl_xor(v, m);
  return v;
}
__device__ __forceinline__ float wave_max_all(float v) {
#pragma unroll
  for (int m = 1; m < 64; m <<= 1) v = fmaxf(v, __shfl_xor(v, m));
  return v;
}

// serial per-node gather (fallback path only)
template <int D>
__device__ __forceinline__ float gather_row(const int* __restrict__ crow,
                                            const float* __restrict__ cval,
                                            const float* __restrict__ Z, int e0, int e1,
                                            int jj) {
  float acc0 = 0.f, acc1 = 0.f, acc2 = 0.f, acc3 = 0.f;
  int e = e0;
  for (; e + 4 <= e1; e += 4) {
    int r0 = crow[e], r1 = crow[e + 1], r2 = crow[e + 2], r3 = crow[e + 3];
    float v0 = cval[e], v1 = cval[e + 1], v2 = cval[e + 2], v3 = cval[e + 3];
    float z0 = Z[(size_t)r0 * D + jj];
    float z1 = Z[(size_t)r1 * D + jj];
    float z2 = Z[(size_t)r2 * D + jj];
    float z3 = Z[(size_t)r3 * D + jj];
    acc0 += v0 * z0;
    acc1 += v1 * z1;
    acc2 += v2 * z2;
    acc3 += v3 * z3;
  }
  for (; e < e1; ++e) acc0 += cval[e] * Z[(size_t)crow[e] * D + jj];
  return (acc0 + acc1) + (acc2 + acc3);
}

// ---------------- build helpers ----------------

__global__ __launch_bounds__(THREADS) void zero_i32(int* p, int n) {
  int i = blockIdx.x * THREADS + threadIdx.x;
  if (i < n) p[i] = 0;
}

__global__ __launch_bounds__(THREADS) void init_power(float* v, float* norm2, int n, float c) {
  int i = blockIdx.x * THREADS + threadIdx.x;
  if (i < n) v[i] = c;
  if (blockIdx.x == 0 && threadIdx.x < 64) norm2[threadIdx.x] = 0.f;
}

__global__ __launch_bounds__(THREADS) void hist_deg(const int* __restrict__ row,
                                                    const int* __restrict__ col,
                                                    int* rdeg, int* cdeg, int E) {
  int e = blockIdx.x * THREADS + threadIdx.x;
  if (e < E) {
    atomicAdd(&rdeg[row[e]], 1);
    atomicAdd(&cdeg[col[e]], 1);
  }
}

__global__ __launch_bounds__(THREADS) void scan1(const int* __restrict__ in, int* bsum, int L) {
  __shared__ int lds[THREADS];
  int idx = blockIdx.x * THREADS + threadIdx.x;
  lds[threadIdx.x] = (idx < L) ? in[idx] : 0;
  __syncthreads();
  for (int off = THREADS / 2; off > 0; off >>= 1) {
    if (threadIdx.x < off) lds[threadIdx.x] += lds[threadIdx.x + off];
    __syncthreads();
  }
  if (threadIdx.x == 0) bsum[blockIdx.x] = lds[0];
}

__global__ __launch_bounds__(THREADS) void scan2(int* bsum, int B) {
  __shared__ int lds[THREADS];
  int t = threadIdx.x;
  lds[t] = (t < B) ? bsum[t] : 0;
  __syncthreads();
  for (int off = 1; off < THREADS; off <<= 1) {
    int add = (t >= off) ? lds[t - off] : 0;
    __syncthreads();
    lds[t] += add;
    __syncthreads();
  }
  if (t < B) bsum[t] = (t == 0) ? 0 : lds[t - 1];
}

__global__ __launch_bounds__(THREADS) void scan3(int* data, const int* __restrict__ bsum, int L) {
  __shared__ int lds[THREADS];
  int t = threadIdx.x;
  int idx = blockIdx.x * THREADS + t;
  int v = (idx < L) ? data[idx] : 0;
  lds[t] = v;
  __syncthreads();
  for (int off = 1; off < THREADS; off <<= 1) {
    int add = (t >= off) ? lds[t - off] : 0;
    __syncthreads();
    lds[t] += add;
    __syncthreads();
  }
  if (idx < L) data[idx] = lds[t] - v + bsum[blockIdx.x];
}

__global__ __launch_bounds__(THREADS) void scatter_edges(
    const int* __restrict__ row, const int* __restrict__ col, const float* __restrict__ val,
    const int* __restrict__ rstart, int* rcur, int* csr_col, float* csr_val,
    const int* __restrict__ cstart, int* ccur, int* csc_row, float* csc_val, int E) {
  int e = blockIdx.x * THREADS + threadIdx.x;
  if (e < E) {
    int r = row[e], c = col[e];
    float v = val[e];
    int p = rstart[r] + atomicAdd(&rcur[r], 1);
    csr_col[p] = c;
    csr_val[p] = v;
    int q = cstart[c] + atomicAdd(&ccur[c], 1);
    csc_row[q] = r;
    csc_val[q] = v;
  }
}

// ---------------- power iteration: 4 lanes per node ----------------
__global__ __launch_bounds__(THREADS) void power_spmv4(
    const int* __restrict__ rs, const int* __restrict__ rcol, const float* __restrict__ rval,
    const float* __restrict__ vin, float* __restrict__ vout, float* norm2, int k, int n) {
  int gid = blockIdx.x * THREADS + threadIdx.x;
  int node = gid >> 2;
  int sl = gid & 3;
  float inv = (k == 1) ? 1.0f : 1.0f / (sqrtf(norm2[k - 1]) + 1e-12f);
  float a0 = 0.f, a1 = 0.f, a2 = 0.f, a3 = 0.f;
  if (node < n) {
    int e0 = rs[node], e1 = rs[node + 1];
    int e = e0 + sl;
    for (; e + 12 < e1; e += 16) {
      int r0 = rcol[e], r1 = rcol[e + 4], r2 = rcol[e + 8], r3 = rcol[e + 12];
      float v0 = rval[e], v1 = rval[e + 4], v2 = rval[e + 8], v3 = rval[e + 12];
      a0 += v0 * vin[r0];
      a1 += v1 * vin[r1];
      a2 += v2 * vin[r2];
      a3 += v3 * vin[r3];
    }
    for (; e < e1; e += 4) a0 += rval[e] * vin[rcol[e]];
  }
  float w = (a0 + a1) + (a2 + a3);
  w += __shfl_xor(w, 1);
  w += __shfl_xor(w, 2);
  w *= inv;
  float sq = 0.f;
  if (node < n && sl == 0) {
    vout[node] = w;
    sq = w * w;
  }
#pragma unroll
  for (int off = 32; off > 0; off >>= 1) sq += __shfl_down(sq, off);
  if ((threadIdx.x & 63) == 0) atomicAdd(&norm2[k], sq);
}

// ---------------- transposes ----------------

__global__ __launch_bounds__(256) void transpose_feat(const float* __restrict__ in,
                                                      float* __restrict__ out, int n) {
  __shared__ float tile[32][33];
  int bx = blockIdx.x;
  int by = blockIdx.y;
  int x = bx * 32 + threadIdx.x;
  for (int dy = threadIdx.y; dy < 32; dy += 8) {
    int y = by * 32 + dy;
    tile[dy][threadIdx.x] = (x < n) ? in[(size_t)y * n + x] : 0.f;
  }
  __syncthreads();
  for (int dy = threadIdx.y; dy < 32; dy += 8) {
    int node = bx * 32 + dy;
    int feat = by * 32 + threadIdx.x;
    if (node < n) out[(size_t)node * 128 + feat] = tile[threadIdx.x][dy];
  }
}

__global__ __launch_bounds__(THREADS) void transpose_small(const float* __restrict__ in,
                                                           float* __restrict__ out, int rows,
                                                           int cols) {
  int idx = blockIdx.x * THREADS + threadIdx.x;
  if (idx < rows * cols) {
    int r = idx / cols, c = idx % cols;
    out[c * rows + r] = in[idx];
  }
}

// ---------------- projection (row-wise L1 projection via bisection) ----------------
template <int D>
__global__ __launch_bounds__(64) void project_row(const float* __restrict__ W,
                                                  float* __restrict__ WpT,
                                                  const float* __restrict__ norm2) {
  int o = blockIdx.x;
  int l = threadIdx.x;
  float rho = sqrtf(norm2[51]) + 1e-12f;
  float k = 0.9f / rho;
  float a0 = (l < D) ? W[o * D + l] : 0.f;
  float a1 = (64 + l < D) ? W[o * D + 64 + l] : 0.f;
  float ab0 = fabsf(a0), ab1 = fabsf(a1);
  float s = wave_sum_all(ab0 + ab1);
  float mx = wave_max_all(fmaxf(ab0, ab1));
  float w0 = a0, w1 = a1;
  if (s > k) {
    float lo = 0.f, hi = mx;
    for (int it = 0; it < 50; ++it) {
      float mid = 0.5f * (lo + hi);
      float g = wave_sum_all(fmaxf(ab0 - mid, 0.f) + fmaxf(ab1 - mid, 0.f));
      if (g > k) lo = mid; else hi = mid;
    }
    float theta = 0.5f * (lo + hi);
    w0 = copysignf(fmaxf(ab0 - theta, 0.f), a0);
    w1 = copysignf(fmaxf(ab1 - theta, 0.f), a1);
  }
  if (l < D) WpT[l * D + o] = w0;
  if (64 + l < D) WpT[(64 + l) * D + o] = w1;
}

// ---------------- edge-parallel gather into LDS tile sT[DOUT][NB+1] ----------------
// All 4 waves stream the block's contiguous CSC edge range; 8 edges in flight per
// wave; ds_add_f32 accumulation (stride-33 rows -> 2-way bank aliasing, free).
template <int DOUT, int NB, int EMAX, int UN>
__device__ __forceinline__ void edge_gather(const int* __restrict__ cstart,
                                            const int* __restrict__ crow,
                                            const float* __restrict__ cval,
                                            const float* __restrict__ Zin,
                                            float (*sT)[NB + 1], unsigned short* eown,
                                            int node0, int n) {
  constexpr int NW = THREADS / 64;
  constexpr int LPE = (DOUT < 64) ? DOUT : 64;   // lanes per edge sub-row
  constexpr int SUBW = 64 / LPE;                 // edges per wave in parallel
  constexpr int WPE = (DOUT + 63) / 64;          // waves per edge (2 for DOUT=128)
  constexpr int NS = (NW / WPE) * SUBW;          // independent edge streams
  const int tid = threadIdx.x;
  // zero the tile
  for (int i = tid; i < DOUT * (NB + 1); i += THREADS) ((float*)sT)[i] = 0.f;
  const int nend = (node0 + NB < n) ? node0 + NB : n;
  const int ebase = cstart[node0];
  const int eend = cstart[nend];
  const bool fits = (eend - ebase) <= EMAX;
  if (fits) {
    for (int nn = tid; nn < NB; nn += THREADS) {
      int node = node0 + nn;
      if (node < n) {
        int s = cstart[node], t = cstart[node + 1];
        for (int e = s; e < t; ++e) eown[e - ebase] = (unsigned short)nn;
      }
    }
  }
  __syncthreads();
  if (fits) {
    const int wid = tid >> 6, lane = tid & 63;
    const int jj = (lane % LPE) + ((WPE > 1) ? (wid % WPE) * 64 : 0);
    const int sub = lane / LPE;
    const int sid = (wid / WPE) * SUBW + sub;
    for (int e0 = ebase + sid * UN; e0 < eend; e0 += NS * UN) {
      float zv[UN], vv[UN];
      int ow[UN];
#pragma unroll
      for (int u = 0; u < UN; ++u) {
        int ee = e0 + u;
        bool ok = ee < eend;
        int r = ok ? crow[ee] : 0;
        vv[u] = ok ? cval[ee] : 0.f;
        ow[u] = ok ? (int)eown[ee - ebase] : 0;
        zv[u] = Zin[(size_t)r * DOUT + jj];
      }
#pragma unroll
      for (int u = 0; u < UN; ++u) atomicAdd(&sT[jj][ow[u]], vv[u] * zv[u]);
    }
  } else {
    // fallback: per-node serial gather (statistically never taken)
    constexpr int LG = THREADS / DOUT;
    const int jf = tid % DOUT;
    const int lg = tid / DOUT;
    for (int nn = lg; nn < NB; nn += LG) {
      int node = node0 + nn;
      if (node < n) {
        int e0 = cstart[node], e1 = cstart[node + 1];
        sT[jf][nn] = gather_row<DOUT>(crow, cval, Zin, e0, e1, jf);
      }
    }
  }
  __syncthreads();
}

// ---------------- spmm for bt (+ Z init = relu(bt)) ----------------
template <int DOUT, int NB, int EMAX, int UN>
__global__ __launch_bounds__(THREADS, 4) void spmm_bt_ep(
    const int* __restrict__ cstart, const int* __restrict__ crow, const float* __restrict__ cval,
    const float* __restrict__ X, float* __restrict__ bt, float* __restrict__ Zinit, int n) {
  __shared__ float sT[DOUT][NB + 1];
  __shared__ unsigned short eown[EMAX];
  const int node0 = blockIdx.x * NB;
  edge_gather<DOUT, NB, EMAX, UN>(cstart, crow, cval, X, sT, eown, node0, n);
  const int tid = threadIdx.x;
  for (int i = tid; i < NB * DOUT; i += THREADS) {
    int nn = i / DOUT, jj = i % DOUT;
    int node = node0 + nn;
    if (node < n) {
      float v = sT[jj][nn];
      bt[(size_t)node * DOUT + jj] = v;
      Zinit[(size_t)node * DOUT + jj] = fmaxf(v, 0.f);
    }
  }
}

// ---------------- fused fixed-point step: Zout = relu( (A^T Zin) @ WpT + bt ) ------
template <int DOUT, int NB, int EMAX, int UN>
__global__ __launch_bounds__(THREADS, 4) void fp_step(
    const int* __restrict__ cstart, const int* __restrict__ crow, const float* __restrict__ cval,
    const float* __restrict__ Zin, const float* __restrict__ WpT, const float* __restrict__ bt,
    float* __restrict__ Zout, int n) {
  constexpr int TO = DOUT / 4;
  constexpr int TN = THREADS / TO;
  constexpr int NT = NB / TN;
  __shared__ float sT[DOUT][NB + 1];
  __shared__ unsigned short eown[EMAX];
  const int node0 = blockIdx.x * NB;
  const int tid = threadIdx.x;
  // phase 1: edge-parallel gather
  edge_gather<DOUT, NB, EMAX, UN>(cstart, crow, cval, Zin, sT, eown, node0, n);
  // phase 2: register-tiled GEMM  C[n][o] = sum_j S[n][j] * WpT[j][o]
  const int o4 = tid % TO, tg = tid / TO;
  const int o0 = o4 * 4;
  float acc[NT][4];
#pragma unroll
  for (int a = 0; a < NT; ++a) acc[a][0] = acc[a][1] = acc[a][2] = acc[a][3] = 0.f;
  for (int jz = 0; jz < DOUT; ++jz) {
    const float4 w4 = *(const float4*)&WpT[jz * DOUT + o0];
#pragma unroll
    for (int a = 0; a < NT; ++a) {
      float sv = sT[jz][tg * NT + a];
      acc[a][0] += sv * w4.x;
      acc[a][1] += sv * w4.y;
      acc[a][2] += sv * w4.z;
      acc[a][3] += sv * w4.w;
    }
  }
#pragma unroll
  for (int a = 0; a < NT; ++a) {
    int node = node0 + tg * NT + a;
    if (node < n) {
      const float4 b4 = *(const float4*)&bt[(size_t)node * DOUT + o0];
      float4 z;
      z.x = fmaxf(acc[a][0] + b4.x, 0.f);
      z.y = fmaxf(acc[a][1] + b4.y, 0.f);
      z.z = fmaxf(acc[a][2] + b4.z, 0.f);
      z.w = fmaxf(acc[a][3] + b4.w, 0.f);
      *(float4*)&Zout[(size_t)node * DOUT + o0] = z;
    }
  }
}

// ---------------- dense GEMM: Out = act( X @ MT + bias + Add ) ----------------
template <int DOUT, int NB>
__global__ __launch_bounds__(THREADS) void dense_gemm(
    const float* __restrict__ X, int din, const float* __restrict__ MT,
    const float* __restrict__ bias, const float* __restrict__ Add, int act,
    float* __restrict__ Out, int n) {
  constexpr int TO = DOUT / 4;
  constexpr int TN = THREADS / TO;
  constexpr int NT = NB / TN;
  __shared__ float xs[NB][129];
  const int node0 = blockIdx.x * NB;
  const int tid = threadIdx.x;
  for (int idx = tid; idx < NB * din; idx += THREADS) {
    int nn = idx / din, j = idx % din;
    int node = node0 + nn;
    xs[nn][j] = (node < n) ? X[(size_t)node * din + j] : 0.f;
  }
  __syncthreads();
  const int o4 = tid % TO, tg = tid / TO;
  const int o0 = o4 * 4;
  float acc[NT][4];
#pragma unroll
  for (int a = 0; a < NT; ++a) acc[a][0] = acc[a][1] = acc[a][2] = acc[a][3] = 0.f;
  for (int j = 0; j < din; ++j) {
    const float4 m4 = *(const float4*)&MT[j * DOUT + o0];
#pragma unroll
    for (int a = 0; a < NT; ++a) {
      float sv = xs[tg * NT + a][j];
      acc[a][0] += sv * m4.x;
      acc[a][1] += sv * m4.y;
      acc[a][2] += sv * m4.z;
      acc[a][3] += sv * m4.w;
    }
  }
#pragma unroll
  for (int a = 0; a < NT; ++a) {
    int node = node0 + tg * NT + a;
    if (node < n) {
      float4 r;
      r.x = acc[a][0]; r.y = acc[a][1]; r.z = acc[a][2]; r.w = acc[a][3];
      if (bias) {
        r.x += bias[o0]; r.y += bias[o0 + 1]; r.z += bias[o0 + 2]; r.w += bias[o0 + 3];
      }
      if (Add) {
        const float4 a4 = *(const float4*)&Add[(size_t)node * DOUT + o0];
        r.x += a4.x; r.y += a4.y; r.z += a4.z; r.w += a4.w;
      }
      if (act == 1) {
        r.x = (r.x > 0.f) ? r.x : expm1f(r.x);
        r.y = (r.y > 0.f) ? r.y : expm1f(r.y);
        r.z = (r.z > 0.f) ? r.z : expm1f(r.z);
        r.w = (r.w > 0.f) ? r.w : expm1f(r.w);
      }
      *(float4*)&Out[(size_t)node * DOUT + o0] = r;
    }
  }
}

// ---------------- host-side dispatch ----------------

static void launch_project(int dout, const float* W, float* WpT, const float* norm2,
                           hipStream_t s) {
  switch (dout) {
    case 128: project_row<128><<<128, 64, 0, s>>>(W, WpT, norm2); break;
    case 64: project_row<64><<<64, 64, 0, s>>>(W, WpT, norm2); break;
    case 32: project_row<32><<<32, 64, 0, s>>>(W, WpT, norm2); break;
    case 16: project_row<16><<<16, 64, 0, s>>>(W, WpT, norm2); break;
  }
}

static void launch_spmm_bt(int dout, const int* cs, const int* cr, const float* cv,
                           const float* X, float* bt, float* Zi, int n, hipStream_t s) {
  switch (dout) {
    case 128: spmm_bt_ep<128, 32, 1280, 8><<<ceil_div(n, 32), THREADS, 0, s>>>(cs, cr, cv, X, bt, Zi, n); break;
    case 64: spmm_bt_ep<64, 32, 1280, 8><<<ceil_div(n, 32), THREADS, 0, s>>>(cs, cr, cv, X, bt, Zi, n); break;
    case 32: spmm_bt_ep<32, 32, 1280, 8><<<ceil_div(n, 32), THREADS, 0, s>>>(cs, cr, cv, X, bt, Zi, n); break;
    case 16: spmm_bt_ep<16, 64, 2560, 4><<<ceil_div(n, 64), THREADS, 0, s>>>(cs, cr, cv, X, bt, Zi, n); break;
  }
}

static void launch_fp_step(int dout, const int* cs, const int* cr, const float* cv,
                           const float* Zin, const float* WpT, const float* bt, float* Zout,
                           int n, hipStream_t s) {
  switch (dout) {
    case 128: fp_step<128, 32, 1280, 8><<<ceil_div(n, 32), THREADS, 0, s>>>(cs, cr, cv, Zin, WpT, bt, Zout, n); break;
    case 64: fp_step<64, 32, 1280, 8><<<ceil_div(n, 32), THREADS, 0, s>>>(cs, cr, cv, Zin, WpT, bt, Zout, n); break;
    case 32: fp_step<32, 32, 1280, 8><<<ceil_div(n, 32), THREADS, 0, s>>>(cs, cr, cv, Zin, WpT, bt, Zout, n); break;
    case 16: fp_step<16, 64, 2560, 4><<<ceil_div(n, 64), THREADS, 0, s>>>(cs, cr, cv, Zin, WpT, bt, Zout, n); break;
  }
}

static void launch_dense_gemm(int dout, const float* X, int din, const float* MT,
                              const float* bias, const float* Add, int act, float* Out, int n,
                              hipStream_t s) {
  switch (dout) {
    case 128: dense_gemm<128, 32><<<ceil_div(n, 32), THREADS, 0, s>>>(X, din, MT, bias, Add, act, Out, n); break;
    case 64: dense_gemm<64, 32><<<ceil_div(n, 32), THREADS, 0, s>>>(X, din, MT, bias, Add, act, Out, n); break;
    case 32: dense_gemm<32, 32><<<ceil_div(n, 32), THREADS, 0, s>>>(X, din, MT, bias, Add, act, Out, n); break;
    case 16: dense_gemm<16, 64><<<ceil_div(n, 64), THREADS, 0, s>>>(X, din, MT, bias, Add, act, Out, n); break;
  }
}

extern "C" void kernel_launch(void* const* d_in, const int* in_sizes, int n_in, void* d_out,
                              int out_size, void* d_ws, size_t ws_size, hipStream_t stream) {
  const float* features = (const float*)d_in[0];
  const int* row = (const int*)d_in[1];
  const int* col = (const int*)d_in[2];
  const float* val = (const float*)d_in[3];
  const int N = in_sizes[0] / 128;
  const int E = in_sizes[1];
  static const int DIN[5] = {128, 128, 64, 64, 32};
  static const int DOUT[5] = {128, 64, 64, 32, 16};

  char* base = (char*)d_ws;
  size_t off = 0;
  auto alloc = [&](size_t bytes) -> void* {
    off = (off + 255) & ~(size_t)255;
    void* p = (void*)(base + off);
    off += bytes;
    return p;
  };

  int* rstart = (int*)alloc((size_t)(N + 1) * 4);
  int* cstart = (int*)alloc((size_t)(N + 1) * 4);
  int* rcur = (int*)alloc((size_t)N * 4);
  int* ccur = (int*)alloc((size_t)N * 4);
  int* bsum = (int*)alloc(256 * 4);
  float* norm2 = (float*)alloc(64 * 4);
  float* v_a = (float*)alloc((size_t)N * 4);
  float* v_b = (float*)alloc((size_t)N * 4);
  int* csr_col = (int*)alloc((size_t)E * 4);
  float* csr_val = (float*)alloc((size_t)E * 4);
  int* csc_row = (int*)alloc((size_t)E * 4);
  float* csc_val = (float*)alloc((size_t)E * 4);
  float* WpT = (float*)alloc(16384 * 4);
  float* OmT = (float*)alloc(16384 * 4);
  float* PwT = (float*)alloc(16384 * 4);
  float* x0 = (float*)alloc((size_t)N * 128 * 4);
  float* x1 = (float*)alloc((size_t)N * 128 * 4);
  float* xom = (float*)alloc((size_t)N * 128 * 4);
  float* btb = (float*)alloc((size_t)N * 128 * 4);
  float* z_a = (float*)alloc((size_t)N * 128 * 4);
  float* z_b = (float*)alloc((size_t)N * 128 * 4);

  const int gN = ceil_div(N, THREADS);
  const int gE = ceil_div(E, THREADS);
  const int L = N + 1;
  const int B = ceil_div(L, THREADS);

  // ---- build CSR/CSC ----
  zero_i32<<<ceil_div(N + 1, THREADS), THREADS, 0, stream>>>(rstart, N + 1);
  zero_i32<<<ceil_div(N + 1, THREADS), THREADS, 0, stream>>>(cstart, N + 1);
  zero_i32<<<gN, THREADS, 0, stream>>>(rcur, N);
  zero_i32<<<gN, THREADS, 0, stream>>>(ccur, N);
  init_power<<<gN, THREADS, 0, stream>>>(v_a, norm2, N, (float)(1.0 / sqrt((double)N)));
  hist_deg<<<gE, THREADS, 0, stream>>>(row, col, rstart, cstart, E);
  scan1<<<B, THREADS, 0, stream>>>(rstart, bsum, L);
  scan2<<<1, THREADS, 0, stream>>>(bsum, B);
  scan3<<<B, THREADS, 0, stream>>>(rstart, bsum, L);
  scan1<<<B, THREADS, 0, stream>>>(cstart, bsum, L);
  scan2<<<1, THREADS, 0, stream>>>(bsum, B);
  scan3<<<B, THREADS, 0, stream>>>(cstart, bsum, L);
  scatter_edges<<<gE, THREADS, 0, stream>>>(row, col, val, rstart, rcur, csr_col, csr_val,
                                            cstart, ccur, csc_row, csc_val, E);

  // ---- x = features^T ----
  {
    dim3 grid(ceil_div(N, 32), 4);
    dim3 block(32, 8);
    transpose_feat<<<grid, block, 0, stream>>>(features, x0, N);
  }

  // ---- spectral radius: 50 power iterations + final norm (51 spmv) ----
  {
    int g4 = ceil_div(N * 4, THREADS);
    for (int k = 1; k <= 51; ++k) {
      const float* vin = (k & 1) ? v_a : v_b;
      float* vout = (k & 1) ? v_b : v_a;
      power_spmv4<<<g4, THREADS, 0, stream>>>(rstart, csr_col, csr_val, vin, vout, norm2, k, N);
    }
  }

  // ---- layers ----
  float* xcur = x0;
  float* xnext = x1;
  for (int i = 0; i < 5; ++i) {
    const int din = DIN[i], dout = DOUT[i];
    const float* W = (const float*)d_in[4 + 4 * i];
    const float* Om = (const float*)d_in[5 + 4 * i];
    const float* Pw = (const float*)d_in[6 + 4 * i];
    const float* Pb = (const float*)d_in[7 + 4 * i];

    transpose_small<<<ceil_div(dout * din, THREADS), THREADS, 0, stream>>>(Om, OmT, dout, din);
    transpose_small<<<ceil_div(dout * din, THREADS), THREADS, 0, stream>>>(Pw, PwT, dout, din);
    launch_project(dout, W, WpT, norm2, stream);

    // xom = x @ Om^T
    launch_dense_gemm(dout, xcur, din, OmT, nullptr, nullptr, 0, xom, N, stream);
    // bt = A^T xom ; z_a = relu(bt)   (== fixed-point iteration 1 of 15)
    launch_spmm_bt(dout, cstart, csc_row, csc_val, xom, btb, z_a, N, stream);
    // remaining 14 iterations; ends in z_a (14 is even)
    for (int s = 0; s < 14; ++s) {
      const float* zin = (s & 1) ? z_b : z_a;
      float* zout = (s & 1) ? z_a : z_b;
      launch_fp_step(dout, cstart, csc_row, csc_val, zin, WpT, btb, zout, N, stream);
    }
    // x = z + x @ Pw^T + Pb ; elu for layers 0..3; layer 4 -> d_out
    float* outp = (i < 4) ? xnext : (float*)d_out;
    launch_dense_gemm(dout, xcur, din, PwT, Pb, z_a, (i < 4) ? 1 : 0, outp, N, stream);
    float* t = xcur; xcur = xnext; xnext = t;
  }
}

// Round 4
// 6138.836 us; speedup vs baseline: 4.4742x; 4.4742x over previous
//
#include <hip/hip_runtime.h>
#include <math.h>

#define THREADS 256

static inline int ceil_div(int a, int b) { return (a + b - 1) / b; }

__device__ __forceinline__ float wave_sum_all(float v) {
#pragma unroll
  for (int m = 1; m < 64; m <<= 1) v += __shfl_xor(v, m);
  return v;
}
__device__ __forceinline__ float wave_max_all(float v) {
#pragma unroll
  for (int m = 1; m < 64; m <<= 1) v = fmaxf(v, __shfl_xor(v, m));
  return v;
}

// 8-wide predicated sparse gather: sum_e cval[e] * Z[crow[e]*D + jj]
// Predication (not a remainder loop) keeps 8 independent loads in flight
// every round; inactive slots read row 0 with weight 0 (L1-resident, harmless).
template <int D>
__device__ __forceinline__ float gather_row(const int* __restrict__ crow,
                                            const float* __restrict__ cval,
                                            const float* __restrict__ Z, int e0, int e1,
                                            int jj) {
  float acc0 = 0.f, acc1 = 0.f, acc2 = 0.f, acc3 = 0.f;
  float acc4 = 0.f, acc5 = 0.f, acc6 = 0.f, acc7 = 0.f;
  for (int e = e0; e < e1; e += 8) {
    int r[8];
    float v[8];
#pragma unroll
    for (int u = 0; u < 8; ++u) {
      int ee = e + u;
      bool ok = ee < e1;
      r[u] = ok ? crow[ee] : 0;
      v[u] = ok ? cval[ee] : 0.f;
    }
    float z0 = Z[(size_t)r[0] * D + jj];
    float z1 = Z[(size_t)r[1] * D + jj];
    float z2 = Z[(size_t)r[2] * D + jj];
    float z3 = Z[(size_t)r[3] * D + jj];
    float z4 = Z[(size_t)r[4] * D + jj];
    float z5 = Z[(size_t)r[5] * D + jj];
    float z6 = Z[(size_t)r[6] * D + jj];
    float z7 = Z[(size_t)r[7] * D + jj];
    acc0 += v[0] * z0;
    acc1 += v[1] * z1;
    acc2 += v[2] * z2;
    acc3 += v[3] * z3;
    acc4 += v[4] * z4;
    acc5 += v[5] * z5;
    acc6 += v[6] * z6;
    acc7 += v[7] * z7;
  }
  return ((acc0 + acc1) + (acc2 + acc3)) + ((acc4 + acc5) + (acc6 + acc7));
}

// ---------------- build helpers ----------------

__global__ __launch_bounds__(THREADS) void zero_i32(int* p, int n) {
  int i = blockIdx.x * THREADS + threadIdx.x;
  if (i < n) p[i] = 0;
}

__global__ __launch_bounds__(THREADS) void init_power(float* v, float* norm2, int n, float c) {
  int i = blockIdx.x * THREADS + threadIdx.x;
  if (i < n) v[i] = c;
  if (blockIdx.x == 0 && threadIdx.x < 64) norm2[threadIdx.x] = 0.f;
}

__global__ __launch_bounds__(THREADS) void hist_deg(const int* __restrict__ row,
                                                    const int* __restrict__ col,
                                                    int* rdeg, int* cdeg, int E) {
  int e = blockIdx.x * THREADS + threadIdx.x;
  if (e < E) {
    atomicAdd(&rdeg[row[e]], 1);
    atomicAdd(&cdeg[col[e]], 1);
  }
}

__global__ __launch_bounds__(THREADS) void scan1(const int* __restrict__ in, int* bsum, int L) {
  __shared__ int lds[THREADS];
  int idx = blockIdx.x * THREADS + threadIdx.x;
  lds[threadIdx.x] = (idx < L) ? in[idx] : 0;
  __syncthreads();
  for (int off = THREADS / 2; off > 0; off >>= 1) {
    if (threadIdx.x < off) lds[threadIdx.x] += lds[threadIdx.x + off];
    __syncthreads();
  }
  if (threadIdx.x == 0) bsum[blockIdx.x] = lds[0];
}

__global__ __launch_bounds__(THREADS) void scan2(int* bsum, int B) {
  __shared__ int lds[THREADS];
  int t = threadIdx.x;
  lds[t] = (t < B) ? bsum[t] : 0;
  __syncthreads();
  for (int off = 1; off < THREADS; off <<= 1) {
    int add = (t >= off) ? lds[t - off] : 0;
    __syncthreads();
    lds[t] += add;
    __syncthreads();
  }
  if (t < B) bsum[t] = (t == 0) ? 0 : lds[t - 1];
}

__global__ __launch_bounds__(THREADS) void scan3(int* data, const int* __restrict__ bsum, int L) {
  __shared__ int lds[THREADS];
  int t = threadIdx.x;
  int idx = blockIdx.x * THREADS + t;
  int v = (idx < L) ? data[idx] : 0;
  lds[t] = v;
  __syncthreads();
  for (int off = 1; off < THREADS; off <<= 1) {
    int add = (t >= off) ? lds[t - off] : 0;
    __syncthreads();
    lds[t] += add;
    __syncthreads();
  }
  if (idx < L) data[idx] = lds[t] - v + bsum[blockIdx.x];
}

__global__ __launch_bounds__(THREADS) void scatter_edges(
    const int* __restrict__ row, const int* __restrict__ col, const float* __restrict__ val,
    const int* __restrict__ rstart, int* rcur, int* csr_col, float* csr_val,
    const int* __restrict__ cstart, int* ccur, int* csc_row, float* csc_val, int E) {
  int e = blockIdx.x * THREADS + threadIdx.x;
  if (e < E) {
    int r = row[e], c = col[e];
    float v = val[e];
    int p = rstart[r] + atomicAdd(&rcur[r], 1);
    csr_col[p] = c;
    csr_val[p] = v;
    int q = cstart[c] + atomicAdd(&ccur[c], 1);
    csc_row[q] = r;
    csc_val[q] = v;
  }
}

// ---------------- power iteration (UNNORMALIZED chain) ----------------
// v_{k+1} = A v_k with no normalization; rho = ||v51||/||v50|| at the end.
// Mathematically identical to normalizing every step; removes the serial
// scalar dependency between launches. rho^50 stays comfortably in f32 range.
__global__ __launch_bounds__(THREADS) void power_spmv_nn(
    const int* __restrict__ rs, const int* __restrict__ rcol, const float* __restrict__ rval,
    const float* __restrict__ vin, float* __restrict__ vout, int n) {
  int gid = blockIdx.x * THREADS + threadIdx.x;
  int node = gid >> 2;
  int sl = gid & 3;
  if (node >= n) return;
  int e0 = rs[node], e1 = rs[node + 1];
  float a0 = 0.f, a1 = 0.f, a2 = 0.f, a3 = 0.f;
  for (int e = e0 + sl; e < e1; e += 16) {
    int ee1 = e + 4, ee2 = e + 8, ee3 = e + 12;
    bool k1 = ee1 < e1, k2 = ee2 < e1, k3 = ee3 < e1;
    int r0 = rcol[e];
    int r1 = k1 ? rcol[ee1] : 0;
    int r2 = k2 ? rcol[ee2] : 0;
    int r3 = k3 ? rcol[ee3] : 0;
    float v0 = rval[e];
    float v1 = k1 ? rval[ee1] : 0.f;
    float v2 = k2 ? rval[ee2] : 0.f;
    float v3 = k3 ? rval[ee3] : 0.f;
    a0 += v0 * vin[r0];
    a1 += v1 * vin[r1];
    a2 += v2 * vin[r2];
    a3 += v3 * vin[r3];
  }
  float w = (a0 + a1) + (a2 + a3);
  w += __shfl_xor(w, 1);
  w += __shfl_xor(w, 2);
  if (sl == 0) vout[node] = w;
}

// n2[0] += ||u||^2 ; n2[1] += ||w||^2
__global__ __launch_bounds__(THREADS) void norm2_pair(const float* __restrict__ u,
                                                      const float* __restrict__ w,
                                                      float* norm2, int n) {
  int i = blockIdx.x * THREADS + threadIdx.x;
  float a = (i < n) ? u[i] : 0.f;
  float b = (i < n) ? w[i] : 0.f;
  float sa = wave_sum_all(a * a);
  float sb = wave_sum_all(b * b);
  __shared__ float pa[4], pb[4];
  if ((threadIdx.x & 63) == 0) {
    pa[threadIdx.x >> 6] = sa;
    pb[threadIdx.x >> 6] = sb;
  }
  __syncthreads();
  if (threadIdx.x == 0) atomicAdd(&norm2[0], pa[0] + pa[1] + pa[2] + pa[3]);
  if (threadIdx.x == 64) atomicAdd(&norm2[1], pb[0] + pb[1] + pb[2] + pb[3]);
}

// ---------------- transposes ----------------

__global__ __launch_bounds__(256) void transpose_feat(const float* __restrict__ in,
                                                      float* __restrict__ out, int n) {
  __shared__ float tile[32][33];
  int bx = blockIdx.x;
  int by = blockIdx.y;
  int x = bx * 32 + threadIdx.x;
  for (int dy = threadIdx.y; dy < 32; dy += 8) {
    int y = by * 32 + dy;
    tile[dy][threadIdx.x] = (x < n) ? in[(size_t)y * n + x] : 0.f;
  }
  __syncthreads();
  for (int dy = threadIdx.y; dy < 32; dy += 8) {
    int node = bx * 32 + dy;
    int feat = by * 32 + threadIdx.x;
    if (node < n) out[(size_t)node * 128 + feat] = tile[threadIdx.x][dy];
  }
}

__global__ __launch_bounds__(THREADS) void transpose_small(const float* __restrict__ in,
                                                           float* __restrict__ out, int rows,
                                                           int cols) {
  int idx = blockIdx.x * THREADS + threadIdx.x;
  if (idx < rows * cols) {
    int r = idx / cols, c = idx % cols;
    out[c * rows + r] = in[idx];
  }
}

// ---------------- projection (row-wise L1 projection via bisection) ----------------
template <int D>
__global__ __launch_bounds__(64) void project_row(const float* __restrict__ W,
                                                  float* __restrict__ WpT,
                                                  const float* __restrict__ norm2) {
  int o = blockIdx.x;
  int l = threadIdx.x;
  float rho = sqrtf(norm2[0] / norm2[1]) + 1e-12f;
  float k = 0.9f / rho;
  float a0 = (l < D) ? W[o * D + l] : 0.f;
  float a1 = (64 + l < D) ? W[o * D + 64 + l] : 0.f;
  float ab0 = fabsf(a0), ab1 = fabsf(a1);
  float s = wave_sum_all(ab0 + ab1);
  float mx = wave_max_all(fmaxf(ab0, ab1));
  float w0 = a0, w1 = a1;
  if (s > k) {
    float lo = 0.f, hi = mx;
    for (int it = 0; it < 50; ++it) {
      float mid = 0.5f * (lo + hi);
      float g = wave_sum_all(fmaxf(ab0 - mid, 0.f) + fmaxf(ab1 - mid, 0.f));
      if (g > k) lo = mid; else hi = mid;
    }
    float theta = 0.5f * (lo + hi);
    w0 = copysignf(fmaxf(ab0 - theta, 0.f), a0);
    w1 = copysignf(fmaxf(ab1 - theta, 0.f), a1);
  }
  if (l < D) WpT[l * D + o] = w0;
  if (64 + l < D) WpT[(64 + l) * D + o] = w1;
}

// ---------------- spmm for bt (+ Z init = relu(bt)) ----------------
template <int DOUT>
__global__ __launch_bounds__(THREADS, 6) void spmm_bt(
    const int* __restrict__ cstart, const int* __restrict__ crow, const float* __restrict__ cval,
    const float* __restrict__ X, float* __restrict__ bt, float* __restrict__ Zinit, int n) {
  int idx = blockIdx.x * THREADS + threadIdx.x;
  int node = idx / DOUT;
  int jj = idx % DOUT;
  if (node >= n) return;
  int e0 = cstart[node], e1 = cstart[node + 1];
  float acc = gather_row<DOUT>(crow, cval, X, e0, e1, jj);
  bt[idx] = acc;
  Zinit[idx] = fmaxf(acc, 0.f);
}

// ---------------- fused fixed-point step: Zout = relu( (A^T Zin) @ WpT + bt ) ------
template <int DOUT, int NB>
__global__ __launch_bounds__(THREADS, 6) void fp_step(
    const int* __restrict__ cstart, const int* __restrict__ crow, const float* __restrict__ cval,
    const float* __restrict__ Zin, const float* __restrict__ WpT, const float* __restrict__ bt,
    float* __restrict__ Zout, int n) {
  constexpr int LG = THREADS / DOUT;
  constexpr int TO = DOUT / 4;
  constexpr int TN = THREADS / TO;
  constexpr int NT = NB / TN;
  static_assert(NT >= 1, "NB too small");
  __shared__ float sT[DOUT][NB + 1];
  const int node0 = blockIdx.x * NB;
  const int tid = threadIdx.x;
  // phase 1: gather S rows (transposed into LDS), 8 loads in flight
  {
    const int jj = tid % DOUT;
    const int lg = tid / DOUT;
    for (int nn = lg; nn < NB; nn += LG) {
      int node = node0 + nn;
      float acc = 0.f;
      if (node < n) {
        int e0 = cstart[node], e1 = cstart[node + 1];
        acc = gather_row<DOUT>(crow, cval, Zin, e0, e1, jj);
      }
      sT[jj][nn] = acc;
    }
  }
  __syncthreads();
  // phase 2: register-tiled GEMM  C[n][o] = sum_j S[n][j] * WpT[j][o]
  const int o4 = tid % TO, tg = tid / TO;
  const int o0 = o4 * 4;
  float acc[NT][4];
#pragma unroll
  for (int a = 0; a < NT; ++a) acc[a][0] = acc[a][1] = acc[a][2] = acc[a][3] = 0.f;
  for (int jz = 0; jz < DOUT; ++jz) {
    const float4 w4 = *(const float4*)&WpT[jz * DOUT + o0];
#pragma unroll
    for (int a = 0; a < NT; ++a) {
      float sv = sT[jz][tg * NT + a];
      acc[a][0] += sv * w4.x;
      acc[a][1] += sv * w4.y;
      acc[a][2] += sv * w4.z;
      acc[a][3] += sv * w4.w;
    }
  }
#pragma unroll
  for (int a = 0; a < NT; ++a) {
    int node = node0 + tg * NT + a;
    if (node < n) {
      const float4 b4 = *(const float4*)&bt[(size_t)node * DOUT + o0];
      float4 z;
      z.x = fmaxf(acc[a][0] + b4.x, 0.f);
      z.y = fmaxf(acc[a][1] + b4.y, 0.f);
      z.z = fmaxf(acc[a][2] + b4.z, 0.f);
      z.w = fmaxf(acc[a][3] + b4.w, 0.f);
      *(float4*)&Zout[(size_t)node * DOUT + o0] = z;
    }
  }
}

// ---------------- dense GEMM: Out = act( X @ MT + bias + Add ) ----------------
template <int DOUT, int NB>
__global__ __launch_bounds__(THREADS) void dense_gemm(
    const float* __restrict__ X, int din, const float* __restrict__ MT,
    const float* __restrict__ bias, const float* __restrict__ Add, int act,
    float* __restrict__ Out, int n) {
  constexpr int TO = DOUT / 4;
  constexpr int TN = THREADS / TO;
  constexpr int NT = NB / TN;
  __shared__ float xs[NB][129];
  const int node0 = blockIdx.x * NB;
  const int tid = threadIdx.x;
  for (int idx = tid; idx < NB * din; idx += THREADS) {
    int nn = idx / din, j = idx % din;
    int node = node0 + nn;
    xs[nn][j] = (node < n) ? X[(size_t)node * din + j] : 0.f;
  }
  __syncthreads();
  const int o4 = tid % TO, tg = tid / TO;
  const int o0 = o4 * 4;
  float acc[NT][4];
#pragma unroll
  for (int a = 0; a < NT; ++a) acc[a][0] = acc[a][1] = acc[a][2] = acc[a][3] = 0.f;
  for (int j = 0; j < din; ++j) {
    const float4 m4 = *(const float4*)&MT[j * DOUT + o0];
#pragma unroll
    for (int a = 0; a < NT; ++a) {
      float sv = xs[tg * NT + a][j];
      acc[a][0] += sv * m4.x;
      acc[a][1] += sv * m4.y;
      acc[a][2] += sv * m4.z;
      acc[a][3] += sv * m4.w;
    }
  }
#pragma unroll
  for (int a = 0; a < NT; ++a) {
    int node = node0 + tg * NT + a;
    if (node < n) {
      float4 r;
      r.x = acc[a][0]; r.y = acc[a][1]; r.z = acc[a][2]; r.w = acc[a][3];
      if (bias) {
        r.x += bias[o0]; r.y += bias[o0 + 1]; r.z += bias[o0 + 2]; r.w += bias[o0 + 3];
      }
      if (Add) {
        const float4 a4 = *(const float4*)&Add[(size_t)node * DOUT + o0];
        r.x += a4.x; r.y += a4.y; r.z += a4.z; r.w += a4.w;
      }
      if (act == 1) {
        r.x = (r.x > 0.f) ? r.x : expm1f(r.x);
        r.y = (r.y > 0.f) ? r.y : expm1f(r.y);
        r.z = (r.z > 0.f) ? r.z : expm1f(r.z);
        r.w = (r.w > 0.f) ? r.w : expm1f(r.w);
      }
      *(float4*)&Out[(size_t)node * DOUT + o0] = r;
    }
  }
}

// ---------------- host-side dispatch ----------------

static void launch_project(int dout, const float* W, float* WpT, const float* norm2,
                           hipStream_t s) {
  switch (dout) {
    case 128: project_row<128><<<128, 64, 0, s>>>(W, WpT, norm2); break;
    case 64: project_row<64><<<64, 64, 0, s>>>(W, WpT, norm2); break;
    case 32: project_row<32><<<32, 64, 0, s>>>(W, WpT, norm2); break;
    case 16: project_row<16><<<16, 64, 0, s>>>(W, WpT, norm2); break;
  }
}

static void launch_spmm_bt(int dout, const int* cs, const int* cr, const float* cv,
                           const float* X, float* bt, float* Zi, int n, hipStream_t s) {
  int g = ceil_div(n * dout, THREADS);
  switch (dout) {
    case 128: spmm_bt<128><<<g, THREADS, 0, s>>>(cs, cr, cv, X, bt, Zi, n); break;
    case 64: spmm_bt<64><<<g, THREADS, 0, s>>>(cs, cr, cv, X, bt, Zi, n); break;
    case 32: spmm_bt<32><<<g, THREADS, 0, s>>>(cs, cr, cv, X, bt, Zi, n); break;
    case 16: spmm_bt<16><<<g, THREADS, 0, s>>>(cs, cr, cv, X, bt, Zi, n); break;
  }
}

static void launch_fp_step(int dout, const int* cs, const int* cr, const float* cv,
                           const float* Zin, const float* WpT, const float* bt, float* Zout,
                           int n, hipStream_t s) {
  switch (dout) {
    case 128: fp_step<128, 16><<<ceil_div(n, 16), THREADS, 0, s>>>(cs, cr, cv, Zin, WpT, bt, Zout, n); break;
    case 64: fp_step<64, 16><<<ceil_div(n, 16), THREADS, 0, s>>>(cs, cr, cv, Zin, WpT, bt, Zout, n); break;
    case 32: fp_step<32, 32><<<ceil_div(n, 32), THREADS, 0, s>>>(cs, cr, cv, Zin, WpT, bt, Zout, n); break;
    case 16: fp_step<16, 64><<<ceil_div(n, 64), THREADS, 0, s>>>(cs, cr, cv, Zin, WpT, bt, Zout, n); break;
  }
}

static void launch_dense_gemm(int dout, const float* X, int din, const float* MT,
                              const float* bias, const float* Add, int act, float* Out, int n,
                              hipStream_t s) {
  switch (dout) {
    case 128: dense_gemm<128, 32><<<ceil_div(n, 32), THREADS, 0, s>>>(X, din, MT, bias, Add, act, Out, n); break;
    case 64: dense_gemm<64, 32><<<ceil_div(n, 32), THREADS, 0, s>>>(X, din, MT, bias, Add, act, Out, n); break;
    case 32: dense_gemm<32, 32><<<ceil_div(n, 32), THREADS, 0, s>>>(X, din, MT, bias, Add, act, Out, n); break;
    case 16: dense_gemm<16, 64><<<ceil_div(n, 64), THREADS, 0, s>>>(X, din, MT, bias, Add, act, Out, n); break;
  }
}

extern "C" void kernel_launch(void* const* d_in, const int* in_sizes, int n_in, void* d_out,
                              int out_size, void* d_ws, size_t ws_size, hipStream_t stream) {
  const float* features = (const float*)d_in[0];
  const int* row = (const int*)d_in[1];
  const int* col = (const int*)d_in[2];
  const float* val = (const float*)d_in[3];
  const int N = in_sizes[0] / 128;
  const int E = in_sizes[1];
  static const int DIN[5] = {128, 128, 64, 64, 32};
  static const int DOUT[5] = {128, 64, 64, 32, 16};

  char* base = (char*)d_ws;
  size_t off = 0;
  auto alloc = [&](size_t bytes) -> void* {
    off = (off + 255) & ~(size_t)255;
    void* p = (void*)(base + off);
    off += bytes;
    return p;
  };

  int* rstart = (int*)alloc((size_t)(N + 1) * 4);
  int* cstart = (int*)alloc((size_t)(N + 1) * 4);
  int* rcur = (int*)alloc((size_t)N * 4);
  int* ccur = (int*)alloc((size_t)N * 4);
  int* bsum = (int*)alloc(256 * 4);
  float* norm2 = (float*)alloc(64 * 4);
  float* v_a = (float*)alloc((size_t)N * 4);
  float* v_b = (float*)alloc((size_t)N * 4);
  int* csr_col = (int*)alloc((size_t)E * 4);
  float* csr_val = (float*)alloc((size_t)E * 4);
  int* csc_row = (int*)alloc((size_t)E * 4);
  float* csc_val = (float*)alloc((size_t)E * 4);
  float* WpT = (float*)alloc(16384 * 4);
  float* OmT = (float*)alloc(16384 * 4);
  float* PwT = (float*)alloc(16384 * 4);
  float* x0 = (float*)alloc((size_t)N * 128 * 4);
  float* x1 = (float*)alloc((size_t)N * 128 * 4);
  float* xom = (float*)alloc((size_t)N * 128 * 4);
  float* btb = (float*)alloc((size_t)N * 128 * 4);
  float* z_a = (float*)alloc((size_t)N * 128 * 4);
  float* z_b = (float*)alloc((size_t)N * 128 * 4);

  const int gN = ceil_div(N, THREADS);
  const int gE = ceil_div(E, THREADS);
  const int L = N + 1;
  const int B = ceil_div(L, THREADS);

  // ---- build CSR/CSC ----
  zero_i32<<<ceil_div(N + 1, THREADS), THREADS, 0, stream>>>(rstart, N + 1);
  zero_i32<<<ceil_div(N + 1, THREADS), THREADS, 0, stream>>>(cstart, N + 1);
  zero_i32<<<gN, THREADS, 0, stream>>>(rcur, N);
  zero_i32<<<gN, THREADS, 0, stream>>>(ccur, N);
  init_power<<<gN, THREADS, 0, stream>>>(v_a, norm2, N, (float)(1.0 / sqrt((double)N)));
  hist_deg<<<gE, THREADS, 0, stream>>>(row, col, rstart, cstart, E);
  scan1<<<B, THREADS, 0, stream>>>(rstart, bsum, L);
  scan2<<<1, THREADS, 0, stream>>>(bsum, B);
  scan3<<<B, THREADS, 0, stream>>>(rstart, bsum, L);
  scan1<<<B, THREADS, 0, stream>>>(cstart, bsum, L);
  scan2<<<1, THREADS, 0, stream>>>(bsum, B);
  scan3<<<B, THREADS, 0, stream>>>(cstart, bsum, L);
  scatter_edges<<<gE, THREADS, 0, stream>>>(row, col, val, rstart, rcur, csr_col, csr_val,
                                            cstart, ccur, csc_row, csc_val, E);

  // ---- x = features^T ----
  {
    dim3 grid(ceil_div(N, 32), 4);
    dim3 block(32, 8);
    transpose_feat<<<grid, block, 0, stream>>>(features, x0, N);
  }

  // ---- spectral radius: 51 unnormalized SpMVs, then one ratio-norm ----
  {
    int g4 = ceil_div(N * 4, THREADS);
    for (int k = 1; k <= 51; ++k) {
      const float* vin = (k & 1) ? v_a : v_b;
      float* vout = (k & 1) ? v_b : v_a;
      power_spmv_nn<<<g4, THREADS, 0, stream>>>(rstart, csr_col, csr_val, vin, vout, N);
    }
    // v50 ended in v_a (k=50 writes v_a), v51 in v_b (k=51 writes v_b)
    norm2_pair<<<gN, THREADS, 0, stream>>>(v_b, v_a, norm2, N);
  }

  // ---- layers ----
  float* xcur = x0;
  float* xnext = x1;
  for (int i = 0; i < 5; ++i) {
    const int din = DIN[i], dout = DOUT[i];
    const float* W = (const float*)d_in[4 + 4 * i];
    const float* Om = (const float*)d_in[5 + 4 * i];
    const float* Pw = (const float*)d_in[6 + 4 * i];
    const float* Pb = (const float*)d_in[7 + 4 * i];

    transpose_small<<<ceil_div(dout * din, THREADS), THREADS, 0, stream>>>(Om, OmT, dout, din);
    transpose_small<<<ceil_div(dout * din, THREADS), THREADS, 0, stream>>>(Pw, PwT, dout, din);
    launch_project(dout, W, WpT, norm2, stream);

    // xom = x @ Om^T
    launch_dense_gemm(dout, xcur, din, OmT, nullptr, nullptr, 0, xom, N, stream);
    // bt = A^T xom ; z_a = relu(bt)   (== fixed-point iteration 1 of 15)
    launch_spmm_bt(dout, cstart, csc_row, csc_val, xom, btb, z_a, N, stream);
    // remaining 14 iterations; ends in z_a (14 is even)
    for (int s = 0; s < 14; ++s) {
      const float* zin = (s & 1) ? z_b : z_a;
      float* zout = (s & 1) ? z_a : z_b;
      launch_fp_step(dout, cstart, csc_row, csc_val, zin, WpT, btb, zout, N, stream);
    }
    // x = z + x @ Pw^T + Pb ; elu for layers 0..3; layer 4 -> d_out
    float* outp = (i < 4) ? xnext : (float*)d_out;
    launch_dense_gemm(dout, xcur, din, PwT, Pb, z_a, (i < 4) ? 1 : 0, outp, N, stream);
    float* t = xcur; xcur = xnext; xnext = t;
  }
}

// Round 5
// 5402.081 us; speedup vs baseline: 5.0844x; 1.1364x over previous
//
#include <hip/hip_runtime.h>
#include <math.h>

#define THREADS 256

static inline int ceil_div(int a, int b) { return (a + b - 1) / b; }

__device__ __forceinline__ float wave_sum_all(float v) {
#pragma unroll
  for (int m = 1; m < 64; m <<= 1) v += __shfl_xor(v, m);
  return v;
}
__device__ __forceinline__ float wave_max_all(float v) {
#pragma unroll
  for (int m = 1; m < 64; m <<= 1) v = fmaxf(v, __shfl_xor(v, m));
  return v;
}

// 8-wide predicated float2 sparse gather:
// returns (sum_e val[e]*Z[row[e]*D+jj2], sum_e val[e]*Z[row[e]*D+jj2+1])
// 8 independent 8B loads in flight per round; inactive slots read row 0 with
// weight 0 (L1-resident, harmless).
template <int D>
__device__ __forceinline__ float2 gather_row2(const int* __restrict__ crow,
                                              const float* __restrict__ cval,
                                              const float* __restrict__ Z, int e0, int e1,
                                              int jj2) {
  float2 acc[8];
#pragma unroll
  for (int u = 0; u < 8; ++u) acc[u] = make_float2(0.f, 0.f);
  for (int e = e0; e < e1; e += 8) {
    int r[8];
    float v[8];
#pragma unroll
    for (int u = 0; u < 8; ++u) {
      int ee = e + u;
      bool ok = ee < e1;
      r[u] = ok ? crow[ee] : 0;
      v[u] = ok ? cval[ee] : 0.f;
    }
    float2 z[8];
#pragma unroll
    for (int u = 0; u < 8; ++u) z[u] = *(const float2*)&Z[(size_t)r[u] * D + jj2];
#pragma unroll
    for (int u = 0; u < 8; ++u) {
      acc[u].x += v[u] * z[u].x;
      acc[u].y += v[u] * z[u].y;
    }
  }
  float2 s01 = make_float2(acc[0].x + acc[1].x, acc[0].y + acc[1].y);
  float2 s23 = make_float2(acc[2].x + acc[3].x, acc[2].y + acc[3].y);
  float2 s45 = make_float2(acc[4].x + acc[5].x, acc[4].y + acc[5].y);
  float2 s67 = make_float2(acc[6].x + acc[7].x, acc[6].y + acc[7].y);
  return make_float2((s01.x + s23.x) + (s45.x + s67.x), (s01.y + s23.y) + (s45.y + s67.y));
}

// ---------------- build helpers ----------------

__global__ __launch_bounds__(THREADS) void zero_i32(int* p, int n) {
  int i = blockIdx.x * THREADS + threadIdx.x;
  if (i < n) p[i] = 0;
}

__global__ __launch_bounds__(THREADS) void init_power(float* v, float* norm2, int n, float c) {
  int i = blockIdx.x * THREADS + threadIdx.x;
  if (i < n) v[i] = c;
  if (blockIdx.x == 0 && threadIdx.x < 64) norm2[threadIdx.x] = 0.f;
}

__global__ __launch_bounds__(THREADS) void hist_deg(const int* __restrict__ row,
                                                    const int* __restrict__ col,
                                                    int* rdeg, int* cdeg, int E) {
  int e = blockIdx.x * THREADS + threadIdx.x;
  if (e < E) {
    atomicAdd(&rdeg[row[e]], 1);
    atomicAdd(&cdeg[col[e]], 1);
  }
}

__global__ __launch_bounds__(THREADS) void scan1(const int* __restrict__ in, int* bsum, int L) {
  __shared__ int lds[THREADS];
  int idx = blockIdx.x * THREADS + threadIdx.x;
  lds[threadIdx.x] = (idx < L) ? in[idx] : 0;
  __syncthreads();
  for (int off = THREADS / 2; off > 0; off >>= 1) {
    if (threadIdx.x < off) lds[threadIdx.x] += lds[threadIdx.x + off];
    __syncthreads();
  }
  if (threadIdx.x == 0) bsum[blockIdx.x] = lds[0];
}

__global__ __launch_bounds__(THREADS) void scan2(int* bsum, int B) {
  __shared__ int lds[THREADS];
  int t = threadIdx.x;
  lds[t] = (t < B) ? bsum[t] : 0;
  __syncthreads();
  for (int off = 1; off < THREADS; off <<= 1) {
    int add = (t >= off) ? lds[t - off] : 0;
    __syncthreads();
    lds[t] += add;
    __syncthreads();
  }
  if (t < B) bsum[t] = (t == 0) ? 0 : lds[t - 1];
}

__global__ __launch_bounds__(THREADS) void scan3(int* data, const int* __restrict__ bsum, int L) {
  __shared__ int lds[THREADS];
  int t = threadIdx.x;
  int idx = blockIdx.x * THREADS + t;
  int v = (idx < L) ? data[idx] : 0;
  lds[t] = v;
  __syncthreads();
  for (int off = 1; off < THREADS; off <<= 1) {
    int add = (t >= off) ? lds[t - off] : 0;
    __syncthreads();
    lds[t] += add;
    __syncthreads();
  }
  if (idx < L) data[idx] = lds[t] - v + bsum[blockIdx.x];
}

__global__ __launch_bounds__(THREADS) void scatter_edges(
    const int* __restrict__ row, const int* __restrict__ col, const float* __restrict__ val,
    const int* __restrict__ rstart, int* rcur, int* csr_col, float* csr_val,
    const int* __restrict__ cstart, int* ccur, int* csc_row, float* csc_val, int E) {
  int e = blockIdx.x * THREADS + threadIdx.x;
  if (e < E) {
    int r = row[e], c = col[e];
    float v = val[e];
    int p = rstart[r] + atomicAdd(&rcur[r], 1);
    csr_col[p] = c;
    csr_val[p] = v;
    int q = cstart[c] + atomicAdd(&ccur[c], 1);
    csc_row[q] = r;
    csc_val[q] = v;
  }
}

// ---------------- power iteration (UNNORMALIZED chain) ----------------
__global__ __launch_bounds__(THREADS) void power_spmv_nn(
    const int* __restrict__ rs, const int* __restrict__ rcol, const float* __restrict__ rval,
    const float* __restrict__ vin, float* __restrict__ vout, int n) {
  int gid = blockIdx.x * THREADS + threadIdx.x;
  int node = gid >> 2;
  int sl = gid & 3;
  if (node >= n) return;
  int e0 = rs[node], e1 = rs[node + 1];
  float a0 = 0.f, a1 = 0.f, a2 = 0.f, a3 = 0.f;
  for (int e = e0 + sl; e < e1; e += 16) {
    int ee1 = e + 4, ee2 = e + 8, ee3 = e + 12;
    bool k1 = ee1 < e1, k2 = ee2 < e1, k3 = ee3 < e1;
    int r0 = rcol[e];
    int r1 = k1 ? rcol[ee1] : 0;
    int r2 = k2 ? rcol[ee2] : 0;
    int r3 = k3 ? rcol[ee3] : 0;
    float v0 = rval[e];
    float v1 = k1 ? rval[ee1] : 0.f;
    float v2 = k2 ? rval[ee2] : 0.f;
    float v3 = k3 ? rval[ee3] : 0.f;
    a0 += v0 * vin[r0];
    a1 += v1 * vin[r1];
    a2 += v2 * vin[r2];
    a3 += v3 * vin[r3];
  }
  float w = (a0 + a1) + (a2 + a3);
  w += __shfl_xor(w, 1);
  w += __shfl_xor(w, 2);
  if (sl == 0) vout[node] = w;
}

// n2[0] += ||u||^2 ; n2[1] += ||w||^2
__global__ __launch_bounds__(THREADS) void norm2_pair(const float* __restrict__ u,
                                                      const float* __restrict__ w,
                                                      float* norm2, int n) {
  int i = blockIdx.x * THREADS + threadIdx.x;
  float a = (i < n) ? u[i] : 0.f;
  float b = (i < n) ? w[i] : 0.f;
  float sa = wave_sum_all(a * a);
  float sb = wave_sum_all(b * b);
  __shared__ float pa[4], pb[4];
  if ((threadIdx.x & 63) == 0) {
    pa[threadIdx.x >> 6] = sa;
    pb[threadIdx.x >> 6] = sb;
  }
  __syncthreads();
  if (threadIdx.x == 0) atomicAdd(&norm2[0], pa[0] + pa[1] + pa[2] + pa[3]);
  if (threadIdx.x == 64) atomicAdd(&norm2[1], pb[0] + pb[1] + pb[2] + pb[3]);
}

// ---------------- transposes ----------------

__global__ __launch_bounds__(256) void transpose_feat(const float* __restrict__ in,
                                                      float* __restrict__ out, int n) {
  __shared__ float tile[32][33];
  int bx = blockIdx.x;
  int by = blockIdx.y;
  int x = bx * 32 + threadIdx.x;
  for (int dy = threadIdx.y; dy < 32; dy += 8) {
    int y = by * 32 + dy;
    tile[dy][threadIdx.x] = (x < n) ? in[(size_t)y * n + x] : 0.f;
  }
  __syncthreads();
  for (int dy = threadIdx.y; dy < 32; dy += 8) {
    int node = bx * 32 + dy;
    int feat = by * 32 + threadIdx.x;
    if (node < n) out[(size_t)node * 128 + feat] = tile[threadIdx.x][dy];
  }
}

__global__ __launch_bounds__(THREADS) void transpose_small(const float* __restrict__ in,
                                                           float* __restrict__ out, int rows,
                                                           int cols) {
  int idx = blockIdx.x * THREADS + threadIdx.x;
  if (idx < rows * cols) {
    int r = idx / cols, c = idx % cols;
    out[c * rows + r] = in[idx];
  }
}

// ---------------- projection (row-wise L1 projection via bisection) ----------------
template <int D>
__global__ __launch_bounds__(64) void project_row(const float* __restrict__ W,
                                                  float* __restrict__ WpT,
                                                  const float* __restrict__ norm2) {
  int o = blockIdx.x;
  int l = threadIdx.x;
  float rho = sqrtf(norm2[0] / norm2[1]) + 1e-12f;
  float k = 0.9f / rho;
  float a0 = (l < D) ? W[o * D + l] : 0.f;
  float a1 = (64 + l < D) ? W[o * D + 64 + l] : 0.f;
  float ab0 = fabsf(a0), ab1 = fabsf(a1);
  float s = wave_sum_all(ab0 + ab1);
  float mx = wave_max_all(fmaxf(ab0, ab1));
  float w0 = a0, w1 = a1;
  if (s > k) {
    float lo = 0.f, hi = mx;
    for (int it = 0; it < 50; ++it) {
      float mid = 0.5f * (lo + hi);
      float g = wave_sum_all(fmaxf(ab0 - mid, 0.f) + fmaxf(ab1 - mid, 0.f));
      if (g > k) lo = mid; else hi = mid;
    }
    float theta = 0.5f * (lo + hi);
    w0 = copysignf(fmaxf(ab0 - theta, 0.f), a0);
    w1 = copysignf(fmaxf(ab1 - theta, 0.f), a1);
  }
  if (l < D) WpT[l * D + o] = w0;
  if (64 + l < D) WpT[(64 + l) * D + o] = w1;
}

// ---------------- spmm for bt (+ Z init = relu(bt)), float2 per thread ---------
template <int DOUT>
__global__ __launch_bounds__(THREADS, 8) void spmm_bt(
    const int* __restrict__ cstart, const int* __restrict__ crow, const float* __restrict__ cval,
    const float* __restrict__ X, float* __restrict__ bt, float* __restrict__ Zinit, int n) {
  constexpr int HD = DOUT / 2;
  int idx = blockIdx.x * THREADS + threadIdx.x;
  int node = idx / HD;
  int jj2 = (idx % HD) * 2;
  if (node >= n) return;
  int e0 = cstart[node], e1 = cstart[node + 1];
  float2 acc = gather_row2<DOUT>(crow, cval, X, e0, e1, jj2);
  size_t o = (size_t)node * DOUT + jj2;
  *(float2*)&bt[o] = acc;
  *(float2*)&Zinit[o] = make_float2(fmaxf(acc.x, 0.f), fmaxf(acc.y, 0.f));
}

// ---------------- fused fixed-point step: Zout = relu( (A^T Zin) @ WpT + bt ) ------
template <int DOUT, int NB>
__global__ __launch_bounds__(THREADS, 8) void fp_step(
    const int* __restrict__ cstart, const int* __restrict__ crow, const float* __restrict__ cval,
    const float* __restrict__ Zin, const float* __restrict__ WpT, const float* __restrict__ bt,
    float* __restrict__ Zout, int n) {
  constexpr int TO = DOUT / 4;
  constexpr int TN = THREADS / TO;
  constexpr int NT = NB / TN;
  static_assert(NT >= 1, "NB too small");
  __shared__ float sT[DOUT][NB + 1];
  const int node0 = blockIdx.x * NB;
  const int tid = threadIdx.x;
  // phase 1: gather S rows (transposed into LDS); float2 per thread,
  // 8 independent 8B loads in flight per window.
  {
    constexpr int HD = DOUT / 2;
    constexpr int LG = THREADS / HD;
    const int jj2 = (tid % HD) * 2;
    const int lg = tid / HD;
    for (int nn = lg; nn < NB; nn += LG) {
      int node = node0 + nn;
      float2 acc = make_float2(0.f, 0.f);
      if (node < n) {
        int e0 = cstart[node], e1 = cstart[node + 1];
        acc = gather_row2<DOUT>(crow, cval, Zin, e0, e1, jj2);
      }
      sT[jj2][nn] = acc.x;
      sT[jj2 + 1][nn] = acc.y;
    }
  }
  __syncthreads();
  // phase 2: register-tiled GEMM  C[n][o] = sum_j S[n][j] * WpT[j][o]
  const int o4 = tid % TO, tg = tid / TO;
  const int o0 = o4 * 4;
  float acc[NT][4];
#pragma unroll
  for (int a = 0; a < NT; ++a) acc[a][0] = acc[a][1] = acc[a][2] = acc[a][3] = 0.f;
  for (int jz = 0; jz < DOUT; ++jz) {
    const float4 w4 = *(const float4*)&WpT[jz * DOUT + o0];
#pragma unroll
    for (int a = 0; a < NT; ++a) {
      float sv = sT[jz][tg * NT + a];
      acc[a][0] += sv * w4.x;
      acc[a][1] += sv * w4.y;
      acc[a][2] += sv * w4.z;
      acc[a][3] += sv * w4.w;
    }
  }
#pragma unroll
  for (int a = 0; a < NT; ++a) {
    int node = node0 + tg * NT + a;
    if (node < n) {
      const float4 b4 = *(const float4*)&bt[(size_t)node * DOUT + o0];
      float4 z;
      z.x = fmaxf(acc[a][0] + b4.x, 0.f);
      z.y = fmaxf(acc[a][1] + b4.y, 0.f);
      z.z = fmaxf(acc[a][2] + b4.z, 0.f);
      z.w = fmaxf(acc[a][3] + b4.w, 0.f);
      *(float4*)&Zout[(size_t)node * DOUT + o0] = z;
    }
  }
}

// ---------------- dense GEMM: Out = act( X @ MT + bias + Add ) ----------------
template <int DOUT, int NB>
__global__ __launch_bounds__(THREADS) void dense_gemm(
    const float* __restrict__ X, int din, const float* __restrict__ MT,
    const float* __restrict__ bias, const float* __restrict__ Add, int act,
    float* __restrict__ Out, int n) {
  constexpr int TO = DOUT / 4;
  constexpr int TN = THREADS / TO;
  constexpr int NT = NB / TN;
  __shared__ float xs[NB][129];
  const int node0 = blockIdx.x * NB;
  const int tid = threadIdx.x;
  for (int idx = tid; idx < NB * din; idx += THREADS) {
    int nn = idx / din, j = idx % din;
    int node = node0 + nn;
    xs[nn][j] = (node < n) ? X[(size_t)node * din + j] : 0.f;
  }
  __syncthreads();
  const int o4 = tid % TO, tg = tid / TO;
  const int o0 = o4 * 4;
  float acc[NT][4];
#pragma unroll
  for (int a = 0; a < NT; ++a) acc[a][0] = acc[a][1] = acc[a][2] = acc[a][3] = 0.f;
  for (int j = 0; j < din; ++j) {
    const float4 m4 = *(const float4*)&MT[j * DOUT + o0];
#pragma unroll
    for (int a = 0; a < NT; ++a) {
      float sv = xs[tg * NT + a][j];
      acc[a][0] += sv * m4.x;
      acc[a][1] += sv * m4.y;
      acc[a][2] += sv * m4.z;
      acc[a][3] += sv * m4.w;
    }
  }
#pragma unroll
  for (int a = 0; a < NT; ++a) {
    int node = node0 + tg * NT + a;
    if (node < n) {
      float4 r;
      r.x = acc[a][0]; r.y = acc[a][1]; r.z = acc[a][2]; r.w = acc[a][3];
      if (bias) {
        r.x += bias[o0]; r.y += bias[o0 + 1]; r.z += bias[o0 + 2]; r.w += bias[o0 + 3];
      }
      if (Add) {
        const float4 a4 = *(const float4*)&Add[(size_t)node * DOUT + o0];
        r.x += a4.x; r.y += a4.y; r.z += a4.z; r.w += a4.w;
      }
      if (act == 1) {
        r.x = (r.x > 0.f) ? r.x : expm1f(r.x);
        r.y = (r.y > 0.f) ? r.y : expm1f(r.y);
        r.z = (r.z > 0.f) ? r.z : expm1f(r.z);
        r.w = (r.w > 0.f) ? r.w : expm1f(r.w);
      }
      *(float4*)&Out[(size_t)node * DOUT + o0] = r;
    }
  }
}

// ---------------- host-side dispatch ----------------

static void launch_project(int dout, const float* W, float* WpT, const float* norm2,
                           hipStream_t s) {
  switch (dout) {
    case 128: project_row<128><<<128, 64, 0, s>>>(W, WpT, norm2); break;
    case 64: project_row<64><<<64, 64, 0, s>>>(W, WpT, norm2); break;
    case 32: project_row<32><<<32, 64, 0, s>>>(W, WpT, norm2); break;
    case 16: project_row<16><<<16, 64, 0, s>>>(W, WpT, norm2); break;
  }
}

static void launch_spmm_bt(int dout, const int* cs, const int* cr, const float* cv,
                           const float* X, float* bt, float* Zi, int n, hipStream_t s) {
  int g = ceil_div(n * dout / 2, THREADS);
  switch (dout) {
    case 128: spmm_bt<128><<<g, THREADS, 0, s>>>(cs, cr, cv, X, bt, Zi, n); break;
    case 64: spmm_bt<64><<<g, THREADS, 0, s>>>(cs, cr, cv, X, bt, Zi, n); break;
    case 32: spmm_bt<32><<<g, THREADS, 0, s>>>(cs, cr, cv, X, bt, Zi, n); break;
    case 16: spmm_bt<16><<<g, THREADS, 0, s>>>(cs, cr, cv, X, bt, Zi, n); break;
  }
}

static void launch_fp_step(int dout, const int* cs, const int* cr, const float* cv,
                           const float* Zin, const float* WpT, const float* bt, float* Zout,
                           int n, hipStream_t s) {
  switch (dout) {
    case 128: fp_step<128, 16><<<ceil_div(n, 16), THREADS, 0, s>>>(cs, cr, cv, Zin, WpT, bt, Zout, n); break;
    case 64: fp_step<64, 16><<<ceil_div(n, 16), THREADS, 0, s>>>(cs, cr, cv, Zin, WpT, bt, Zout, n); break;
    case 32: fp_step<32, 32><<<ceil_div(n, 32), THREADS, 0, s>>>(cs, cr, cv, Zin, WpT, bt, Zout, n); break;
    case 16: fp_step<16, 64><<<ceil_div(n, 64), THREADS, 0, s>>>(cs, cr, cv, Zin, WpT, bt, Zout, n); break;
  }
}

static void launch_dense_gemm(int dout, const float* X, int din, const float* MT,
                              const float* bias, const float* Add, int act, float* Out, int n,
                              hipStream_t s) {
  switch (dout) {
    case 128: dense_gemm<128, 32><<<ceil_div(n, 32), THREADS, 0, s>>>(X, din, MT, bias, Add, act, Out, n); break;
    case 64: dense_gemm<64, 32><<<ceil_div(n, 32), THREADS, 0, s>>>(X, din, MT, bias, Add, act, Out, n); break;
    case 32: dense_gemm<32, 32><<<ceil_div(n, 32), THREADS, 0, s>>>(X, din, MT, bias, Add, act, Out, n); break;
    case 16: dense_gemm<16, 64><<<ceil_div(n, 64), THREADS, 0, s>>>(X, din, MT, bias, Add, act, Out, n); break;
  }
}

extern "C" void kernel_launch(void* const* d_in, const int* in_sizes, int n_in, void* d_out,
                              int out_size, void* d_ws, size_t ws_size, hipStream_t stream) {
  const float* features = (const float*)d_in[0];
  const int* row = (const int*)d_in[1];
  const int* col = (const int*)d_in[2];
  const float* val = (const float*)d_in[3];
  const int N = in_sizes[0] / 128;
  const int E = in_sizes[1];
  static const int DIN[5] = {128, 128, 64, 64, 32};
  static const int DOUT[5] = {128, 64, 64, 32, 16};

  char* base = (char*)d_ws;
  size_t off = 0;
  auto alloc = [&](size_t bytes) -> void* {
    off = (off + 255) & ~(size_t)255;
    void* p = (void*)(base + off);
    off += bytes;
    return p;
  };

  int* rstart = (int*)alloc((size_t)(N + 1) * 4);
  int* cstart = (int*)alloc((size_t)(N + 1) * 4);
  int* rcur = (int*)alloc((size_t)N * 4);
  int* ccur = (int*)alloc((size_t)N * 4);
  int* bsum = (int*)alloc(256 * 4);
  float* norm2 = (float*)alloc(64 * 4);
  float* v_a = (float*)alloc((size_t)N * 4);
  float* v_b = (float*)alloc((size_t)N * 4);
  int* csr_col = (int*)alloc((size_t)E * 4);
  float* csr_val = (float*)alloc((size_t)E * 4);
  int* csc_row = (int*)alloc((size_t)E * 4);
  float* csc_val = (float*)alloc((size_t)E * 4);
  float* WpT = (float*)alloc(16384 * 4);
  float* OmT = (float*)alloc(16384 * 4);
  float* PwT = (float*)alloc(16384 * 4);
  float* x0 = (float*)alloc((size_t)N * 128 * 4);
  float* x1 = (float*)alloc((size_t)N * 128 * 4);
  float* xom = (float*)alloc((size_t)N * 128 * 4);
  float* btb = (float*)alloc((size_t)N * 128 * 4);
  float* z_a = (float*)alloc((size_t)N * 128 * 4);
  float* z_b = (float*)alloc((size_t)N * 128 * 4);

  const int gN = ceil_div(N, THREADS);
  const int gE = ceil_div(E, THREADS);
  const int L = N + 1;
  const int B = ceil_div(L, THREADS);

  // ---- build CSR/CSC ----
  zero_i32<<<ceil_div(N + 1, THREADS), THREADS, 0, stream>>>(rstart, N + 1);
  zero_i32<<<ceil_div(N + 1, THREADS), THREADS, 0, stream>>>(cstart, N + 1);
  zero_i32<<<gN, THREADS, 0, stream>>>(rcur, N);
  zero_i32<<<gN, THREADS, 0, stream>>>(ccur, N);
  init_power<<<gN, THREADS, 0, stream>>>(v_a, norm2, N, (float)(1.0 / sqrt((double)N)));
  hist_deg<<<gE, THREADS, 0, stream>>>(row, col, rstart, cstart, E);
  scan1<<<B, THREADS, 0, stream>>>(rstart, bsum, L);
  scan2<<<1, THREADS, 0, stream>>>(bsum, B);
  scan3<<<B, THREADS, 0, stream>>>(rstart, bsum, L);
  scan1<<<B, THREADS, 0, stream>>>(cstart, bsum, L);
  scan2<<<1, THREADS, 0, stream>>>(bsum, B);
  scan3<<<B, THREADS, 0, stream>>>(cstart, bsum, L);
  scatter_edges<<<gE, THREADS, 0, stream>>>(row, col, val, rstart, rcur, csr_col, csr_val,
                                            cstart, ccur, csc_row, csc_val, E);

  // ---- x = features^T ----
  {
    dim3 grid(ceil_div(N, 32), 4);
    dim3 block(32, 8);
    transpose_feat<<<grid, block, 0, stream>>>(features, x0, N);
  }

  // ---- spectral radius: 51 unnormalized SpMVs, then one ratio-norm ----
  {
    int g4 = ceil_div(N * 4, THREADS);
    for (int k = 1; k <= 51; ++k) {
      const float* vin = (k & 1) ? v_a : v_b;
      float* vout = (k & 1) ? v_b : v_a;
      power_spmv_nn<<<g4, THREADS, 0, stream>>>(rstart, csr_col, csr_val, vin, vout, N);
    }
    // v50 ended in v_a, v51 in v_b
    norm2_pair<<<gN, THREADS, 0, stream>>>(v_b, v_a, norm2, N);
  }

  // ---- layers ----
  float* xcur = x0;
  float* xnext = x1;
  for (int i = 0; i < 5; ++i) {
    const int din = DIN[i], dout = DOUT[i];
    const float* W = (const float*)d_in[4 + 4 * i];
    const float* Om = (const float*)d_in[5 + 4 * i];
    const float* Pw = (const float*)d_in[6 + 4 * i];
    const float* Pb = (const float*)d_in[7 + 4 * i];

    transpose_small<<<ceil_div(dout * din, THREADS), THREADS, 0, stream>>>(Om, OmT, dout, din);
    transpose_small<<<ceil_div(dout * din, THREADS), THREADS, 0, stream>>>(Pw, PwT, dout, din);
    launch_project(dout, W, WpT, norm2, stream);

    // xom = x @ Om^T
    launch_dense_gemm(dout, xcur, din, OmT, nullptr, nullptr, 0, xom, N, stream);
    // bt = A^T xom ; z_a = relu(bt)   (== fixed-point iteration 1 of 15)
    launch_spmm_bt(dout, cstart, csc_row, csc_val, xom, btb, z_a, N, stream);
    // remaining 14 iterations; ends in z_a (14 is even)
    for (int s = 0; s < 14; ++s) {
      const float* zin = (s & 1) ? z_b : z_a;
      float* zout = (s & 1) ? z_a : z_b;
      launch_fp_step(dout, cstart, csc_row, csc_val, zin, WpT, btb, zout, N, stream);
    }
    // x = z + x @ Pw^T + Pb ; elu for layers 0..3; layer 4 -> d_out
    float* outp = (i < 4) ? xnext : (float*)d_out;
    launch_dense_gemm(dout, xcur, din, PwT, Pb, z_a, (i < 4) ? 1 : 0, outp, N, stream);
    float* t = xcur; xcur = xnext; xnext = t;
  }
}

// Round 6
// 4880.140 us; speedup vs baseline: 5.6282x; 1.1070x over previous
//
#include <hip/hip_runtime.h>
#include <hip/hip_fp16.h>
#include <math.h>

#define THREADS 256

static inline int ceil_div(int a, int b) { return (a + b - 1) / b; }

__device__ __forceinline__ float wave_sum_all(float v) {
#pragma unroll
  for (int m = 1; m < 64; m <<= 1) v += __shfl_xor(v, m);
  return v;
}
__device__ __forceinline__ float wave_max_all(float v) {
#pragma unroll
  for (int m = 1; m < 64; m <<= 1) v = fmaxf(v, __shfl_xor(v, m));
  return v;
}

// 8-wide predicated fp16 sparse gather:
// returns (sum_e val[e]*Z[row[e]*D+jj2], sum_e val[e]*Z[row[e]*D+jj2+1])
// 8 independent 4B (half2) loads in flight per round; f32 accumulate.
template <int D>
__device__ __forceinline__ float2 gather_row2h(const int* __restrict__ crow,
                                               const float* __restrict__ cval,
                                               const __half* __restrict__ Z, int e0, int e1,
                                               int jj2) {
  float2 acc[8];
#pragma unroll
  for (int u = 0; u < 8; ++u) acc[u] = make_float2(0.f, 0.f);
  for (int e = e0; e < e1; e += 8) {
    int r[8];
    float v[8];
#pragma unroll
    for (int u = 0; u < 8; ++u) {
      int ee = e + u;
      bool ok = ee < e1;
      r[u] = ok ? crow[ee] : 0;
      v[u] = ok ? cval[ee] : 0.f;
    }
    float2 z[8];
#pragma unroll
    for (int u = 0; u < 8; ++u)
      z[u] = __half22float2(*(const __half2*)&Z[(size_t)r[u] * D + jj2]);
#pragma unroll
    for (int u = 0; u < 8; ++u) {
      acc[u].x += v[u] * z[u].x;
      acc[u].y += v[u] * z[u].y;
    }
  }
  float2 s01 = make_float2(acc[0].x + acc[1].x, acc[0].y + acc[1].y);
  float2 s23 = make_float2(acc[2].x + acc[3].x, acc[2].y + acc[3].y);
  float2 s45 = make_float2(acc[4].x + acc[5].x, acc[4].y + acc[5].y);
  float2 s67 = make_float2(acc[6].x + acc[7].x, acc[6].y + acc[7].y);
  return make_float2((s01.x + s23.x) + (s45.x + s67.x), (s01.y + s23.y) + (s45.y + s67.y));
}

// f32 variant (spmm_bt input xom is f32)
template <int D>
__device__ __forceinline__ float2 gather_row2(const int* __restrict__ crow,
                                              const float* __restrict__ cval,
                                              const float* __restrict__ Z, int e0, int e1,
                                              int jj2) {
  float2 acc[8];
#pragma unroll
  for (int u = 0; u < 8; ++u) acc[u] = make_float2(0.f, 0.f);
  for (int e = e0; e < e1; e += 8) {
    int r[8];
    float v[8];
#pragma unroll
    for (int u = 0; u < 8; ++u) {
      int ee = e + u;
      bool ok = ee < e1;
      r[u] = ok ? crow[ee] : 0;
      v[u] = ok ? cval[ee] : 0.f;
    }
    float2 z[8];
#pragma unroll
    for (int u = 0; u < 8; ++u) z[u] = *(const float2*)&Z[(size_t)r[u] * D + jj2];
#pragma unroll
    for (int u = 0; u < 8; ++u) {
      acc[u].x += v[u] * z[u].x;
      acc[u].y += v[u] * z[u].y;
    }
  }
  float2 s01 = make_float2(acc[0].x + acc[1].x, acc[0].y + acc[1].y);
  float2 s23 = make_float2(acc[2].x + acc[3].x, acc[2].y + acc[3].y);
  float2 s45 = make_float2(acc[4].x + acc[5].x, acc[4].y + acc[5].y);
  float2 s67 = make_float2(acc[6].x + acc[7].x, acc[6].y + acc[7].y);
  return make_float2((s01.x + s23.x) + (s45.x + s67.x), (s01.y + s23.y) + (s45.y + s67.y));
}

// ---------------- build helpers ----------------

__global__ __launch_bounds__(THREADS) void zero_i32(int* p, int n) {
  int i = blockIdx.x * THREADS + threadIdx.x;
  if (i < n) p[i] = 0;
}

__global__ __launch_bounds__(THREADS) void init_power(float* v, float* norm2, int n, float c) {
  int i = blockIdx.x * THREADS + threadIdx.x;
  if (i < n) v[i] = c;
  if (blockIdx.x == 0 && threadIdx.x < 64) norm2[threadIdx.x] = 0.f;
}

__global__ __launch_bounds__(THREADS) void hist_deg(const int* __restrict__ row,
                                                    const int* __restrict__ col,
                                                    int* rdeg, int* cdeg, int E) {
  int e = blockIdx.x * THREADS + threadIdx.x;
  if (e < E) {
    atomicAdd(&rdeg[row[e]], 1);
    atomicAdd(&cdeg[col[e]], 1);
  }
}

__global__ __launch_bounds__(THREADS) void scan1(const int* __restrict__ in, int* bsum, int L) {
  __shared__ int lds[THREADS];
  int idx = blockIdx.x * THREADS + threadIdx.x;
  lds[threadIdx.x] = (idx < L) ? in[idx] : 0;
  __syncthreads();
  for (int off = THREADS / 2; off > 0; off >>= 1) {
    if (threadIdx.x < off) lds[threadIdx.x] += lds[threadIdx.x + off];
    __syncthreads();
  }
  if (threadIdx.x == 0) bsum[blockIdx.x] = lds[0];
}

__global__ __launch_bounds__(THREADS) void scan2(int* bsum, int B) {
  __shared__ int lds[THREADS];
  int t = threadIdx.x;
  lds[t] = (t < B) ? bsum[t] : 0;
  __syncthreads();
  for (int off = 1; off < THREADS; off <<= 1) {
    int add = (t >= off) ? lds[t - off] : 0;
    __syncthreads();
    lds[t] += add;
    __syncthreads();
  }
  if (t < B) bsum[t] = (t == 0) ? 0 : lds[t - 1];
}

__global__ __launch_bounds__(THREADS) void scan3(int* data, const int* __restrict__ bsum, int L) {
  __shared__ int lds[THREADS];
  int t = threadIdx.x;
  int idx = blockIdx.x * THREADS + t;
  int v = (idx < L) ? data[idx] : 0;
  lds[t] = v;
  __syncthreads();
  for (int off = 1; off < THREADS; off <<= 1) {
    int add = (t >= off) ? lds[t - off] : 0;
    __syncthreads();
    lds[t] += add;
    __syncthreads();
  }
  if (idx < L) data[idx] = lds[t] - v + bsum[blockIdx.x];
}

__global__ __launch_bounds__(THREADS) void scatter_edges(
    const int* __restrict__ row, const int* __restrict__ col, const float* __restrict__ val,
    const int* __restrict__ rstart, int* rcur, int* csr_col, float* csr_val,
    const int* __restrict__ cstart, int* ccur, int* csc_row, float* csc_val, int E) {
  int e = blockIdx.x * THREADS + threadIdx.x;
  if (e < E) {
    int r = row[e], c = col[e];
    float v = val[e];
    int p = rstart[r] + atomicAdd(&rcur[r], 1);
    csr_col[p] = c;
    csr_val[p] = v;
    int q = cstart[c] + atomicAdd(&ccur[c], 1);
    csc_row[q] = r;
    csc_val[q] = v;
  }
}

// ---------------- power iteration (UNNORMALIZED chain) ----------------
__global__ __launch_bounds__(THREADS) void power_spmv_nn(
    const int* __restrict__ rs, const int* __restrict__ rcol, const float* __restrict__ rval,
    const float* __restrict__ vin, float* __restrict__ vout, int n) {
  int gid = blockIdx.x * THREADS + threadIdx.x;
  int node = gid >> 2;
  int sl = gid & 3;
  if (node >= n) return;
  int e0 = rs[node], e1 = rs[node + 1];
  float a0 = 0.f, a1 = 0.f, a2 = 0.f, a3 = 0.f;
  for (int e = e0 + sl; e < e1; e += 16) {
    int ee1 = e + 4, ee2 = e + 8, ee3 = e + 12;
    bool k1 = ee1 < e1, k2 = ee2 < e1, k3 = ee3 < e1;
    int r0 = rcol[e];
    int r1 = k1 ? rcol[ee1] : 0;
    int r2 = k2 ? rcol[ee2] : 0;
    int r3 = k3 ? rcol[ee3] : 0;
    float v0 = rval[e];
    float v1 = k1 ? rval[ee1] : 0.f;
    float v2 = k2 ? rval[ee2] : 0.f;
    float v3 = k3 ? rval[ee3] : 0.f;
    a0 += v0 * vin[r0];
    a1 += v1 * vin[r1];
    a2 += v2 * vin[r2];
    a3 += v3 * vin[r3];
  }
  float w = (a0 + a1) + (a2 + a3);
  w += __shfl_xor(w, 1);
  w += __shfl_xor(w, 2);
  if (sl == 0) vout[node] = w;
}

// n2[0] += ||u||^2 ; n2[1] += ||w||^2
__global__ __launch_bounds__(THREADS) void norm2_pair(const float* __restrict__ u,
                                                      const float* __restrict__ w,
                                                      float* norm2, int n) {
  int i = blockIdx.x * THREADS + threadIdx.x;
  float a = (i < n) ? u[i] : 0.f;
  float b = (i < n) ? w[i] : 0.f;
  float sa = wave_sum_all(a * a);
  float sb = wave_sum_all(b * b);
  __shared__ float pa[4], pb[4];
  if ((threadIdx.x & 63) == 0) {
    pa[threadIdx.x >> 6] = sa;
    pb[threadIdx.x >> 6] = sb;
  }
  __syncthreads();
  if (threadIdx.x == 0) atomicAdd(&norm2[0], pa[0] + pa[1] + pa[2] + pa[3]);
  if (threadIdx.x == 64) atomicAdd(&norm2[1], pb[0] + pb[1] + pb[2] + pb[3]);
}

// ---------------- transposes ----------------

__global__ __launch_bounds__(256) void transpose_feat(const float* __restrict__ in,
                                                      float* __restrict__ out, int n) {
  __shared__ float tile[32][33];
  int bx = blockIdx.x;
  int by = blockIdx.y;
  int x = bx * 32 + threadIdx.x;
  for (int dy = threadIdx.y; dy < 32; dy += 8) {
    int y = by * 32 + dy;
    tile[dy][threadIdx.x] = (x < n) ? in[(size_t)y * n + x] : 0.f;
  }
  __syncthreads();
  for (int dy = threadIdx.y; dy < 32; dy += 8) {
    int node = bx * 32 + dy;
    int feat = by * 32 + threadIdx.x;
    if (node < n) out[(size_t)node * 128 + feat] = tile[threadIdx.x][dy];
  }
}

__global__ __launch_bounds__(THREADS) void transpose_small(const float* __restrict__ in,
                                                           float* __restrict__ out, int rows,
                                                           int cols) {
  int idx = blockIdx.x * THREADS + threadIdx.x;
  if (idx < rows * cols) {
    int r = idx / cols, c = idx % cols;
    out[c * rows + r] = in[idx];
  }
}

// ---------------- projection (row-wise L1 projection via bisection) ----------------
template <int D>
__global__ __launch_bounds__(64) void project_row(const float* __restrict__ W,
                                                  float* __restrict__ WpT,
                                                  const float* __restrict__ norm2) {
  int o = blockIdx.x;
  int l = threadIdx.x;
  float rho = sqrtf(norm2[0] / norm2[1]) + 1e-12f;
  float k = 0.9f / rho;
  float a0 = (l < D) ? W[o * D + l] : 0.f;
  float a1 = (64 + l < D) ? W[o * D + 64 + l] : 0.f;
  float ab0 = fabsf(a0), ab1 = fabsf(a1);
  float s = wave_sum_all(ab0 + ab1);
  float mx = wave_max_all(fmaxf(ab0, ab1));
  float w0 = a0, w1 = a1;
  if (s > k) {
    float lo = 0.f, hi = mx;
    for (int it = 0; it < 50; ++it) {
      float mid = 0.5f * (lo + hi);
      float g = wave_sum_all(fmaxf(ab0 - mid, 0.f) + fmaxf(ab1 - mid, 0.f));
      if (g > k) lo = mid; else hi = mid;
    }
    float theta = 0.5f * (lo + hi);
    w0 = copysignf(fmaxf(ab0 - theta, 0.f), a0);
    w1 = copysignf(fmaxf(ab1 - theta, 0.f), a1);
  }
  if (l < D) WpT[l * D + o] = w0;
  if (64 + l < D) WpT[(64 + l) * D + o] = w1;
}

// ---------------- spmm for bt (+ Zinit = relu(bt) in fp16) ----------------
template <int DOUT>
__global__ __launch_bounds__(THREADS, 8) void spmm_bt(
    const int* __restrict__ cstart, const int* __restrict__ crow, const float* __restrict__ cval,
    const float* __restrict__ X, float* __restrict__ bt, __half* __restrict__ Zinit, int n) {
  constexpr int HD = DOUT / 2;
  int idx = blockIdx.x * THREADS + threadIdx.x;
  int node = idx / HD;
  int jj2 = (idx % HD) * 2;
  if (node >= n) return;
  int e0 = cstart[node], e1 = cstart[node + 1];
  float2 acc = gather_row2<DOUT>(crow, cval, X, e0, e1, jj2);
  size_t o = (size_t)node * DOUT + jj2;
  *(float2*)&bt[o] = acc;
  *(__half2*)&Zinit[o] = __floats2half2_rn(fmaxf(acc.x, 0.f), fmaxf(acc.y, 0.f));
}

// ---------------- fused fixed-point step: Zout = relu( (A^T Zin) @ WpT + bt ) ------
// Zin/Zout in fp16; bt, WpT, LDS tile, accumulation in f32.
template <int DOUT, int NB>
__global__ __launch_bounds__(THREADS, 8) void fp_step(
    const int* __restrict__ cstart, const int* __restrict__ crow, const float* __restrict__ cval,
    const __half* __restrict__ Zin, const float* __restrict__ WpT, const float* __restrict__ bt,
    __half* __restrict__ Zout, int n) {
  constexpr int TO = DOUT / 4;
  constexpr int TN = THREADS / TO;
  constexpr int NT = NB / TN;
  static_assert(NT >= 1, "NB too small");
  __shared__ float sT[NB][DOUT + 2];
  const int node0 = blockIdx.x * NB;
  const int tid = threadIdx.x;
  // phase 1: gather S rows into LDS (row-major, float2 writes)
  {
    constexpr int HD = DOUT / 2;
    constexpr int LG = THREADS / HD;
    const int jj2 = (tid % HD) * 2;
    const int lg = tid / HD;
    for (int nn = lg; nn < NB; nn += LG) {
      int node = node0 + nn;
      float2 acc = make_float2(0.f, 0.f);
      if (node < n) {
        int e0 = cstart[node], e1 = cstart[node + 1];
        acc = gather_row2h<DOUT>(crow, cval, Zin, e0, e1, jj2);
      }
      *(float2*)&sT[nn][jj2] = acc;
    }
  }
  __syncthreads();
  // phase 2: register-tiled GEMM  C[n][o] = sum_j S[n][j] * WpT[j][o]
  const int o4 = tid % TO, tg = tid / TO;
  const int o0 = o4 * 4;
  float acc[NT][4];
#pragma unroll
  for (int a = 0; a < NT; ++a) acc[a][0] = acc[a][1] = acc[a][2] = acc[a][3] = 0.f;
  for (int jz = 0; jz < DOUT; ++jz) {
    const float4 w4 = *(const float4*)&WpT[jz * DOUT + o0];
#pragma unroll
    for (int a = 0; a < NT; ++a) {
      float sv = sT[tg * NT + a][jz];
      acc[a][0] += sv * w4.x;
      acc[a][1] += sv * w4.y;
      acc[a][2] += sv * w4.z;
      acc[a][3] += sv * w4.w;
    }
  }
#pragma unroll
  for (int a = 0; a < NT; ++a) {
    int node = node0 + tg * NT + a;
    if (node < n) {
      const float4 b4 = *(const float4*)&bt[(size_t)node * DOUT + o0];
      float zx = fmaxf(acc[a][0] + b4.x, 0.f);
      float zy = fmaxf(acc[a][1] + b4.y, 0.f);
      float zz = fmaxf(acc[a][2] + b4.z, 0.f);
      float zw = fmaxf(acc[a][3] + b4.w, 0.f);
      size_t o = (size_t)node * DOUT + o0;
      *(__half2*)&Zout[o] = __floats2half2_rn(zx, zy);
      *(__half2*)&Zout[o + 2] = __floats2half2_rn(zz, zw);
    }
  }
}

// ---------------- dense GEMM: Out = act( X @ MT + bias + Addh ) ----------------
template <int DOUT, int NB>
__global__ __launch_bounds__(THREADS) void dense_gemm(
    const float* __restrict__ X, int din, const float* __restrict__ MT,
    const float* __restrict__ bias, const __half* __restrict__ Addh, int act,
    float* __restrict__ Out, int n) {
  constexpr int TO = DOUT / 4;
  constexpr int TN = THREADS / TO;
  constexpr int NT = NB / TN;
  __shared__ float xs[NB][129];
  const int node0 = blockIdx.x * NB;
  const int tid = threadIdx.x;
  for (int idx = tid; idx < NB * din; idx += THREADS) {
    int nn = idx / din, j = idx % din;
    int node = node0 + nn;
    xs[nn][j] = (node < n) ? X[(size_t)node * din + j] : 0.f;
  }
  __syncthreads();
  const int o4 = tid % TO, tg = tid / TO;
  const int o0 = o4 * 4;
  float acc[NT][4];
#pragma unroll
  for (int a = 0; a < NT; ++a) acc[a][0] = acc[a][1] = acc[a][2] = acc[a][3] = 0.f;
  for (int j = 0; j < din; ++j) {
    const float4 m4 = *(const float4*)&MT[j * DOUT + o0];
#pragma unroll
    for (int a = 0; a < NT; ++a) {
      float sv = xs[tg * NT + a][j];
      acc[a][0] += sv * m4.x;
      acc[a][1] += sv * m4.y;
      acc[a][2] += sv * m4.z;
      acc[a][3] += sv * m4.w;
    }
  }
#pragma unroll
  for (int a = 0; a < NT; ++a) {
    int node = node0 + tg * NT + a;
    if (node < n) {
      float4 r;
      r.x = acc[a][0]; r.y = acc[a][1]; r.z = acc[a][2]; r.w = acc[a][3];
      if (bias) {
        r.x += bias[o0]; r.y += bias[o0 + 1]; r.z += bias[o0 + 2]; r.w += bias[o0 + 3];
      }
      if (Addh) {
        size_t o = (size_t)node * DOUT + o0;
        float2 a01 = __half22float2(*(const __half2*)&Addh[o]);
        float2 a23 = __half22float2(*(const __half2*)&Addh[o + 2]);
        r.x += a01.x; r.y += a01.y; r.z += a23.x; r.w += a23.y;
      }
      if (act == 1) {
        r.x = (r.x > 0.f) ? r.x : expm1f(r.x);
        r.y = (r.y > 0.f) ? r.y : expm1f(r.y);
        r.z = (r.z > 0.f) ? r.z : expm1f(r.z);
        r.w = (r.w > 0.f) ? r.w : expm1f(r.w);
      }
      *(float4*)&Out[(size_t)node * DOUT + o0] = r;
    }
  }
}

// ---------------- host-side dispatch ----------------

static void launch_project(int dout, const float* W, float* WpT, const float* norm2,
                           hipStream_t s) {
  switch (dout) {
    case 128: project_row<128><<<128, 64, 0, s>>>(W, WpT, norm2); break;
    case 64: project_row<64><<<64, 64, 0, s>>>(W, WpT, norm2); break;
    case 32: project_row<32><<<32, 64, 0, s>>>(W, WpT, norm2); break;
    case 16: project_row<16><<<16, 64, 0, s>>>(W, WpT, norm2); break;
  }
}

static void launch_spmm_bt(int dout, const int* cs, const int* cr, const float* cv,
                           const float* X, float* bt, __half* Zi, int n, hipStream_t s) {
  int g = ceil_div(n * dout / 2, THREADS);
  switch (dout) {
    case 128: spmm_bt<128><<<g, THREADS, 0, s>>>(cs, cr, cv, X, bt, Zi, n); break;
    case 64: spmm_bt<64><<<g, THREADS, 0, s>>>(cs, cr, cv, X, bt, Zi, n); break;
    case 32: spmm_bt<32><<<g, THREADS, 0, s>>>(cs, cr, cv, X, bt, Zi, n); break;
    case 16: spmm_bt<16><<<g, THREADS, 0, s>>>(cs, cr, cv, X, bt, Zi, n); break;
  }
}

static void launch_fp_step(int dout, const int* cs, const int* cr, const float* cv,
                           const __half* Zin, const float* WpT, const float* bt, __half* Zout,
                           int n, hipStream_t s) {
  switch (dout) {
    case 128: fp_step<128, 16><<<ceil_div(n, 16), THREADS, 0, s>>>(cs, cr, cv, Zin, WpT, bt, Zout, n); break;
    case 64: fp_step<64, 16><<<ceil_div(n, 16), THREADS, 0, s>>>(cs, cr, cv, Zin, WpT, bt, Zout, n); break;
    case 32: fp_step<32, 32><<<ceil_div(n, 32), THREADS, 0, s>>>(cs, cr, cv, Zin, WpT, bt, Zout, n); break;
    case 16: fp_step<16, 64><<<ceil_div(n, 64), THREADS, 0, s>>>(cs, cr, cv, Zin, WpT, bt, Zout, n); break;
  }
}

static void launch_dense_gemm(int dout, const float* X, int din, const float* MT,
                              const float* bias, const __half* Addh, int act, float* Out, int n,
                              hipStream_t s) {
  switch (dout) {
    case 128: dense_gemm<128, 32><<<ceil_div(n, 32), THREADS, 0, s>>>(X, din, MT, bias, Addh, act, Out, n); break;
    case 64: dense_gemm<64, 32><<<ceil_div(n, 32), THREADS, 0, s>>>(X, din, MT, bias, Addh, act, Out, n); break;
    case 32: dense_gemm<32, 32><<<ceil_div(n, 32), THREADS, 0, s>>>(X, din, MT, bias, Addh, act, Out, n); break;
    case 16: dense_gemm<16, 64><<<ceil_div(n, 64), THREADS, 0, s>>>(X, din, MT, bias, Addh, act, Out, n); break;
  }
}

extern "C" void kernel_launch(void* const* d_in, const int* in_sizes, int n_in, void* d_out,
                              int out_size, void* d_ws, size_t ws_size, hipStream_t stream) {
  const float* features = (const float*)d_in[0];
  const int* row = (const int*)d_in[1];
  const int* col = (const int*)d_in[2];
  const float* val = (const float*)d_in[3];
  const int N = in_sizes[0] / 128;
  const int E = in_sizes[1];
  static const int DIN[5] = {128, 128, 64, 64, 32};
  static const int DOUT[5] = {128, 64, 64, 32, 16};

  char* base = (char*)d_ws;
  size_t off = 0;
  auto alloc = [&](size_t bytes) -> void* {
    off = (off + 255) & ~(size_t)255;
    void* p = (void*)(base + off);
    off += bytes;
    return p;
  };

  int* rstart = (int*)alloc((size_t)(N + 1) * 4);
  int* cstart = (int*)alloc((size_t)(N + 1) * 4);
  int* rcur = (int*)alloc((size_t)N * 4);
  int* ccur = (int*)alloc((size_t)N * 4);
  int* bsum = (int*)alloc(256 * 4);
  float* norm2 = (float*)alloc(64 * 4);
  float* v_a = (float*)alloc((size_t)N * 4);
  float* v_b = (float*)alloc((size_t)N * 4);
  int* csr_col = (int*)alloc((size_t)E * 4);
  float* csr_val = (float*)alloc((size_t)E * 4);
  int* csc_row = (int*)alloc((size_t)E * 4);
  float* csc_val = (float*)alloc((size_t)E * 4);
  float* WpT = (float*)alloc(16384 * 4);
  float* OmT = (float*)alloc(16384 * 4);
  float* PwT = (float*)alloc(16384 * 4);
  float* x0 = (float*)alloc((size_t)N * 128 * 4);
  float* x1 = (float*)alloc((size_t)N * 128 * 4);
  float* xom = (float*)alloc((size_t)N * 128 * 4);
  float* btb = (float*)alloc((size_t)N * 128 * 4);
  __half* z_a = (__half*)alloc((size_t)N * 128 * 2);
  __half* z_b = (__half*)alloc((size_t)N * 128 * 2);

  const int gN = ceil_div(N, THREADS);
  const int gE = ceil_div(E, THREADS);
  const int L = N + 1;
  const int B = ceil_div(L, THREADS);

  // ---- build CSR/CSC ----
  zero_i32<<<ceil_div(N + 1, THREADS), THREADS, 0, stream>>>(rstart, N + 1);
  zero_i32<<<ceil_div(N + 1, THREADS), THREADS, 0, stream>>>(cstart, N + 1);
  zero_i32<<<gN, THREADS, 0, stream>>>(rcur, N);
  zero_i32<<<gN, THREADS, 0, stream>>>(ccur, N);
  init_power<<<gN, THREADS, 0, stream>>>(v_a, norm2, N, (float)(1.0 / sqrt((double)N)));
  hist_deg<<<gE, THREADS, 0, stream>>>(row, col, rstart, cstart, E);
  scan1<<<B, THREADS, 0, stream>>>(rstart, bsum, L);
  scan2<<<1, THREADS, 0, stream>>>(bsum, B);
  scan3<<<B, THREADS, 0, stream>>>(rstart, bsum, L);
  scan1<<<B, THREADS, 0, stream>>>(cstart, bsum, L);
  scan2<<<1, THREADS, 0, stream>>>(bsum, B);
  scan3<<<B, THREADS, 0, stream>>>(cstart, bsum, L);
  scatter_edges<<<gE, THREADS, 0, stream>>>(row, col, val, rstart, rcur, csr_col, csr_val,
                                            cstart, ccur, csc_row, csc_val, E);

  // ---- x = features^T ----
  {
    dim3 grid(ceil_div(N, 32), 4);
    dim3 block(32, 8);
    transpose_feat<<<grid, block, 0, stream>>>(features, x0, N);
  }

  // ---- spectral radius: 51 unnormalized SpMVs, then one ratio-norm ----
  {
    int g4 = ceil_div(N * 4, THREADS);
    for (int k = 1; k <= 51; ++k) {
      const float* vin = (k & 1) ? v_a : v_b;
      float* vout = (k & 1) ? v_b : v_a;
      power_spmv_nn<<<g4, THREADS, 0, stream>>>(rstart, csr_col, csr_val, vin, vout, N);
    }
    // v50 ended in v_a, v51 in v_b
    norm2_pair<<<gN, THREADS, 0, stream>>>(v_b, v_a, norm2, N);
  }

  // ---- layers ----
  float* xcur = x0;
  float* xnext = x1;
  for (int i = 0; i < 5; ++i) {
    const int din = DIN[i], dout = DOUT[i];
    const float* W = (const float*)d_in[4 + 4 * i];
    const float* Om = (const float*)d_in[5 + 4 * i];
    const float* Pw = (const float*)d_in[6 + 4 * i];
    const float* Pb = (const float*)d_in[7 + 4 * i];

    transpose_small<<<ceil_div(dout * din, THREADS), THREADS, 0, stream>>>(Om, OmT, dout, din);
    transpose_small<<<ceil_div(dout * din, THREADS), THREADS, 0, stream>>>(Pw, PwT, dout, din);
    launch_project(dout, W, WpT, norm2, stream);

    // xom = x @ Om^T
    launch_dense_gemm(dout, xcur, din, OmT, nullptr, nullptr, 0, xom, N, stream);
    // bt = A^T xom ; z_a = relu(bt)   (== fixed-point iteration 1 of 15)
    launch_spmm_bt(dout, cstart, csc_row, csc_val, xom, btb, z_a, N, stream);
    // remaining 14 iterations; ends in z_a (14 is even)
    for (int s = 0; s < 14; ++s) {
      const __half* zin = (s & 1) ? z_b : z_a;
      __half* zout = (s & 1) ? z_a : z_b;
      launch_fp_step(dout, cstart, csc_row, csc_val, zin, WpT, btb, zout, N, stream);
    }
    // x = z + x @ Pw^T + Pb ; elu for layers 0..3; layer 4 -> d_out
    float* outp = (i < 4) ? xnext : (float*)d_out;
    launch_dense_gemm(dout, xcur, din, PwT, Pb, z_a, (i < 4) ? 1 : 0, outp, N, stream);
    float* t = xcur; xcur = xnext; xnext = t;
  }
}